// Round 9
// baseline (10865.820 us; speedup 1.0000x reference)
//
#include <hip/hip_runtime.h>

// Seq2seq LSTM + attention — persistent kernels, contention-free flag barrier.
//
// Round-9 change: deep register prefetch. Round-8 counters showed VGPR=20 on
// the encoder (compiler optimized for occupancy we don't use) => <=2 L3 loads
// in flight against 16 fresh-quad h loads/wave/step => ~2.3us/step serialized
// latency. Now: __launch_bounds__(512,2) (our real occupancy, 256 VGPR cap)
// and explicit float4 a[NQ] prefetch before the FMA loop, in the encoder/
// decoder gate GEMMs and the attention scores/ctx/hq loops.
//
// Decoder algebra (round 8): gates_t = W_h.h_t + W_c.ctx_{t-1} + b' (t>=1),
// W_h = Wih_d.Wo[:,:512]+Whh_d, W_c = Wih_d.Wo[:,512:], b' = b_d+Wih_d.bo;
// t=0 uses Whh_d and g0 = Wih_d.x_last + b_d. One barrier/step; pred column
// via k_dout post-pass.
//
// Barrier: arrival = sc1 store to flags[blockIdx]; wait = wave0 polls all 256.
// All cross-block data written once to never-reused addresses via sc1 stores.

namespace {

__device__ __forceinline__ float fsigmoid(float x) {
    return 1.0f / (1.0f + __expf(-x));
}
__device__ __forceinline__ float ftanh(float x) {
    float e = __expf(2.0f * x);
    return 1.0f - 2.0f / (e + 1.0f);
}

__device__ __forceinline__ void coh_store(float* p, float v) {
    __hip_atomic_store(p, v, __ATOMIC_RELAXED, __HIP_MEMORY_SCOPE_AGENT);
}
__device__ __forceinline__ void coh_store2(float* p, float2 v) {
    union { float2 f; unsigned long long u; } cv; cv.f = v;
    __hip_atomic_store((unsigned long long*)p, cv.u,
                       __ATOMIC_RELAXED, __HIP_MEMORY_SCOPE_AGENT);
}

// ---- contention-free barrier ---------------------------------------------
__device__ __forceinline__ void bar_arrive(unsigned* flags, int bi, unsigned val) {
    if (threadIdx.x < 64) {
        asm volatile("s_waitcnt vmcnt(0)" ::: "memory");
        if (threadIdx.x == 0)
            __hip_atomic_store(&flags[bi], val, __ATOMIC_RELAXED, __HIP_MEMORY_SCOPE_AGENT);
    }
}
__device__ __forceinline__ void bar_wait(const unsigned* flags, unsigned epoch) {
    if (threadIdx.x < 64) {
        const unsigned* f = flags + threadIdx.x * 4;
        for (;;) {
            unsigned a = __hip_atomic_load(f + 0, __ATOMIC_RELAXED, __HIP_MEMORY_SCOPE_AGENT);
            unsigned b = __hip_atomic_load(f + 1, __ATOMIC_RELAXED, __HIP_MEMORY_SCOPE_AGENT);
            unsigned c = __hip_atomic_load(f + 2, __ATOMIC_RELAXED, __HIP_MEMORY_SCOPE_AGENT);
            unsigned d = __hip_atomic_load(f + 3, __ATOMIC_RELAXED, __HIP_MEMORY_SCOPE_AGENT);
            int ok = (a >= epoch) && (b >= epoch) && (c >= epoch) && (d >= epoch);
            if (__all(ok)) break;
            __builtin_amdgcn_s_sleep(1);
        }
    }
    __syncthreads();
}

// ---- transpose input_seq (B,S,F) -> quad layout [s][f/4][b][4] -----------
__global__ __launch_bounds__(256) void k_transpose_input(
    const float* __restrict__ in, float4* __restrict__ xQ)
{
    __shared__ float tile[64][65];
    int s  = blockIdx.x >> 2;
    int f0 = (blockIdx.x & 3) * 64;
    int lane = threadIdx.x & 63;
    int r0   = threadIdx.x >> 6;
    for (int r = r0; r < 64; r += 4)
        tile[r][lane] = in[(size_t)r * (512 * 256) + s * 256 + f0 + lane];
    __syncthreads();
    for (int q = r0; q < 16; q += 4) {
        float4 vv = make_float4(tile[lane][4*q], tile[lane][4*q+1],
                                tile[lane][4*q+2], tile[lane][4*q+3]);
        xQ[((size_t)s * 64 + (f0 >> 2) + q) * 64 + lane] = vv;
    }
}

// ---- small weight/state transposes; encH slot0 quad-packed ---------------
__global__ __launch_bounds__(256) void k_prep(
    const float* __restrict__ We_p, const float* __restrict__ Wh_p,
    const float* __restrict__ h0,   const float* __restrict__ c0,
    const float* __restrict__ Wa,
    float* __restrict__ We_pT, float* __restrict__ Wh_pT,
    float* __restrict__ encH0, float* __restrict__ cT,
    float* __restrict__ WahT,  float* __restrict__ WaeT)
{
    int idx = blockIdx.x * blockDim.x + threadIdx.x;
    const int total = 32768 * 4 + 4096 * 2;
    for (; idx < total; idx += gridDim.x * blockDim.x) {
        if (idx < 32768) {
            int u = idx >> 6, h = idx & 63;
            We_pT[idx] = We_p[h * 512 + u];
        } else if (idx < 65536) {
            int i2 = idx - 32768; int k = i2 >> 6, i = i2 & 63;
            Wh_pT[i2] = Wh_p[i * 512 + k];
        } else if (idx < 98304) {
            int i2 = idx - 65536; int u = i2 >> 6, b = i2 & 63;
            encH0[(u >> 2) * 256 + b * 4 + (u & 3)] = h0[b * 512 + u];
        } else if (idx < 131072) {
            int i2 = idx - 98304; int u = i2 >> 6, b = i2 & 63;
            cT[i2] = c0[b * 512 + u];
        } else if (idx < 135168) {
            int i2 = idx - 131072; int j = i2 >> 6, i = i2 & 63;
            WahT[i2] = Wa[i * 128 + j];
        } else {
            int i2 = idx - 135168; int h2 = i2 >> 6, h = i2 & 63;
            WaeT[i2] = Wa[h * 128 + 64 + h2];
        }
    }
}

// ---- W_h = Wih_d.Wo[:, :512] + Whh_d ; W_c = Wih_d.Wo[:, 512:] ; b' ------
__global__ __launch_bounds__(256) void k_prep_wcomb(
    const float* __restrict__ Wih, const float* __restrict__ Whh,
    const float* __restrict__ Wo,  const float* __restrict__ bd,
    const float* __restrict__ bo,
    float* __restrict__ Wh, float* __restrict__ Wc, float* __restrict__ bprime)
{
    int r = blockIdx.x;          // 0..2047
    for (int j = threadIdx.x; j < 576; j += 256) {
        float acc = 0.f;
        for (int f = 0; f < 256; ++f)
            acc = fmaf(Wih[r * 256 + f], Wo[f * 576 + j], acc);
        if (j < 512) Wh[(size_t)r * 512 + j] = acc + Whh[(size_t)r * 512 + j];
        else         Wc[(size_t)r * 64 + (j - 512)] = acc;
    }
    if (threadIdx.x == 0) {
        float s = bd[r];
        for (int f = 0; f < 256; ++f)
            s = fmaf(Wih[r * 256 + f], bo[f], s);
        bprime[r] = s;
    }
}

// ---- g0[r][b] = Wih_d . x_last + b_d -------------------------------------
__global__ __launch_bounds__(256) void k_prep_g0(
    const float4* __restrict__ xQlast, const float* __restrict__ Wih,
    const float* __restrict__ bd, float* __restrict__ g0)
{
    int r = blockIdx.x * 4 + ((int)threadIdx.x >> 6);
    int lane = threadIdx.x & 63;
    const float4* Wih4 = (const float4*)Wih;
    float acc = bd[r];
    for (int q = 0; q < 64; ++q) {
        float4 a  = xQlast[q * 64 + lane];
        float4 wv = Wih4[(size_t)r * 64 + q];
        acc = fmaf(a.x, wv.x, acc); acc = fmaf(a.y, wv.y, acc);
        acc = fmaf(a.z, wv.z, acc); acc = fmaf(a.w, wv.w, acc);
    }
    g0[(size_t)r * 64 + lane] = acc;
}

// ---- gate-GEMM accumulation, register-prefetched (NQ = 8 or 16) ----------
// Loads all NQ activation quads first (all in flight), then FMAs.
template<int NQ>
__device__ __forceinline__ void accum_seg_pf(
    float acc[8], const float4* __restrict__ actQ, int qb,
    const float4* __restrict__ W4, int wstride, int u0, int lane)
{
    float4 a[NQ];
    #pragma unroll
    for (int q = 0; q < NQ; ++q)
        a[q] = actQ[(qb + q) * 64 + lane];
    #pragma unroll
    for (int q = 0; q < NQ; ++q) {
        #pragma unroll
        for (int uu = 0; uu < 2; ++uu)
            #pragma unroll
            for (int g = 0; g < 4; ++g) {
                float4 wv = W4[(size_t)(g * 512 + u0 + uu) * wstride + (qb + q)];
                float& A = acc[uu * 4 + g];
                A = fmaf(a[q].x, wv.x, A); A = fmaf(a[q].y, wv.y, A);
                A = fmaf(a[q].z, wv.z, A); A = fmaf(a[q].w, wv.w, A);
            }
    }
}

// ---- ctx-part accumulation: 2 quads per wave, prefetched -----------------
__device__ __forceinline__ void accum_ctx(
    float acc[8], const float4* __restrict__ c4,
    const float4* __restrict__ Wc4, int u0, int w, int lane)
{
    float4 a0 = c4[(w * 2 + 0) * 64 + lane];
    float4 a1 = c4[(w * 2 + 1) * 64 + lane];
    #pragma unroll
    for (int uu = 0; uu < 2; ++uu)
        #pragma unroll
        for (int g = 0; g < 4; ++g) {
            float4 w0 = Wc4[(size_t)(g * 512 + u0 + uu) * 16 + w * 2 + 0];
            float4 w1 = Wc4[(size_t)(g * 512 + u0 + uu) * 16 + w * 2 + 1];
            float& A = acc[uu * 4 + g];
            A = fmaf(a0.x, w0.x, A); A = fmaf(a0.y, w0.y, A);
            A = fmaf(a0.z, w0.z, A); A = fmaf(a0.w, w0.w, A);
            A = fmaf(a1.x, w1.x, A); A = fmaf(a1.y, w1.y, A);
            A = fmaf(a1.z, w1.z, A); A = fmaf(a1.w, w1.w, A);
        }
}

// ---- finish variant 1: additive = per-row vector (bias / b') -------------
__device__ __forceinline__ void lstm_finish_vec(
    int u0, int tid, int w, float acc[8], float2& creg,
    const float* __restrict__ addVec, float* __restrict__ houtSlot, float* smem)
{
    int lane = tid & 63;
    float* part = smem;          // [8][8][64]
    float* gsum = smem + 4096;   // [8][64]
    #pragma unroll
    for (int r = 0; r < 8; ++r)
        part[(w * 8 + r) * 64 + lane] = acc[r];
    __syncthreads();
    {
        int b = tid & 63, r = tid >> 6;
        float s = 0.f;
        #pragma unroll
        for (int ww = 0; ww < 8; ++ww)
            s += part[(ww * 8 + r) * 64 + b];
        gsum[r * 64 + b] = s;
    }
    __syncthreads();
    if (tid < 64) {
        int b = tid;
        float cc[2] = {creg.x, creg.y};
        float hv[2];
        #pragma unroll
        for (int uu = 0; uu < 2; ++uu) {
            int u = u0 + uu;
            float gi = gsum[(uu*4+0)*64 + b] + addVec[u];
            float gf = gsum[(uu*4+1)*64 + b] + addVec[512 + u];
            float gg = gsum[(uu*4+2)*64 + b] + addVec[1024 + u];
            float go = gsum[(uu*4+3)*64 + b] + addVec[1536 + u];
            float si = fsigmoid(gi), sf = fsigmoid(gf), so = fsigmoid(go);
            float tg = ftanh(gg);
            float cn = sf * cc[uu] + si * tg;
            cc[uu] = cn;
            hv[uu] = so * ftanh(cn);
        }
        creg = make_float2(cc[0], cc[1]);
        coh_store2(houtSlot + (u0 >> 2) * 256 + b * 4 + (u0 & 3),
                   make_float2(hv[0], hv[1]));
    }
}

// ---- finish variant 2: additive = row x batch buffer (g0) ----------------
__device__ __forceinline__ void lstm_finish_row(
    int u0, int tid, int w, float acc[8], float2& creg,
    const float* __restrict__ addRowB, float* __restrict__ houtSlot, float* smem)
{
    int lane = tid & 63;
    float* part = smem;
    float* gsum = smem + 4096;
    #pragma unroll
    for (int r = 0; r < 8; ++r)
        part[(w * 8 + r) * 64 + lane] = acc[r];
    __syncthreads();
    {
        int b = tid & 63, r = tid >> 6;
        float s = 0.f;
        #pragma unroll
        for (int ww = 0; ww < 8; ++ww)
            s += part[(ww * 8 + r) * 64 + b];
        gsum[r * 64 + b] = s;
    }
    __syncthreads();
    if (tid < 64) {
        int b = tid;
        float cc[2] = {creg.x, creg.y};
        float hv[2];
        #pragma unroll
        for (int uu = 0; uu < 2; ++uu) {
            int u = u0 + uu;
            float gi = gsum[(uu*4+0)*64 + b] + addRowB[(size_t)(0 * 512 + u) * 64 + b];
            float gf = gsum[(uu*4+1)*64 + b] + addRowB[(size_t)(1 * 512 + u) * 64 + b];
            float gg = gsum[(uu*4+2)*64 + b] + addRowB[(size_t)(2 * 512 + u) * 64 + b];
            float go = gsum[(uu*4+3)*64 + b] + addRowB[(size_t)(3 * 512 + u) * 64 + b];
            float si = fsigmoid(gi), sf = fsigmoid(gf), so = fsigmoid(go);
            float tg = ftanh(gg);
            float cn = sf * cc[uu] + si * tg;
            cc[uu] = cn;
            hv[uu] = so * ftanh(cn);
        }
        creg = make_float2(cc[0], cc[1]);
        coh_store2(houtSlot + (u0 >> 2) * 256 + b * 4 + (u0 & 3),
                   make_float2(hv[0], hv[1]));
    }
}

// ---- persistent encoder: overlap x-part(t+1) with barrier ----------------
__global__ __launch_bounds__(512, 2) void k_enc_persistent(
    const float4* __restrict__ xQ, float* __restrict__ encH,
    float* __restrict__ cT,
    const float* __restrict__ Wih, const float* __restrict__ Whh,
    const float* __restrict__ bias, unsigned* flags)
{
    __shared__ float smem[4608];
    int tid = threadIdx.x;
    int lane = tid & 63;
    int w = __builtin_amdgcn_readfirstlane(tid >> 6);
    int bi = blockIdx.x;
    int u0 = bi * 2;
    const float4* Wih4 = (const float4*)Wih;
    const float4* Whh4 = (const float4*)Whh;
    float2 creg = make_float2(0.f, 0.f);
    if (tid < 64) { creg.x = cT[u0 * 64 + tid]; creg.y = cT[(u0 + 1) * 64 + tid]; }
    float acc[8];
    #pragma unroll
    for (int r = 0; r < 8; ++r) acc[r] = 0.f;
    accum_seg_pf<8>(acc, xQ, w * 8, Wih4, 64, u0, lane);       // x-part t=0
    for (int t = 0; t < 512; ++t) {
        bar_wait(flags, (unsigned)t);                           // h[t] ready
        accum_seg_pf<16>(acc, (const float4*)(encH + (size_t)t * 32768),
                         w * 16, Whh4, 128, u0, lane);
        lstm_finish_vec(u0, tid, w, acc, creg, bias,
                        encH + (size_t)(t + 1) * 32768, smem);
        bar_arrive(flags, bi, (unsigned)(t + 1));
        #pragma unroll
        for (int r = 0; r < 8; ++r) acc[r] = 0.f;
        if (t + 1 < 512)   // x-part t+1 under barrier; step stride = 4096 float4
            accum_seg_pf<8>(acc, xQ + (size_t)(t + 1) * 4096, w * 8, Wih4, 64, u0, lane);
    }
    if (tid < 64) { cT[u0 * 64 + tid] = creg.x; cT[(u0 + 1) * 64 + tid] = creg.y; }
}

// ---- enc_proj + enc_attn (ba folded), round-5 form -----------------------
__global__ __launch_bounds__(256) void k_proj_attn(
    const float* __restrict__ encH,  const float* __restrict__ We_pT,
    const float* __restrict__ be_p,  const float* __restrict__ WaeT,
    const float* __restrict__ ba,
    float* __restrict__ encProj, float* __restrict__ attnPre)
{
    int lane = threadIdx.x & 63;
    int w    = __builtin_amdgcn_readfirstlane((int)threadIdx.x >> 6);
    int wid  = blockIdx.x * 4 + w;
    int b    = wid >> 6;
    int soct = wid & 63;
    float acc[8];
    float bep = be_p[lane];
    #pragma unroll
    for (int j = 0; j < 8; ++j) acc[j] = bep;
    #pragma unroll 2
    for (int q = 0; q < 128; ++q) {
        float w0 = We_pT[(4*q+0) * 64 + lane];
        float w1 = We_pT[(4*q+1) * 64 + lane];
        float w2 = We_pT[(4*q+2) * 64 + lane];
        float w3 = We_pT[(4*q+3) * 64 + lane];
        #pragma unroll
        for (int j = 0; j < 8; ++j) {
            const float4* hb4 = (const float4*)(encH + (size_t)(soct*8 + j + 1) * 32768);
            float4 hv = hb4[q * 64 + b];
            acc[j] = fmaf(hv.x, w0, acc[j]); acc[j] = fmaf(hv.y, w1, acc[j]);
            acc[j] = fmaf(hv.z, w2, acc[j]); acc[j] = fmaf(hv.w, w3, acc[j]);
        }
    }
    #pragma unroll
    for (int j = 0; j < 8; ++j)
        encProj[((size_t)b * 512 + soct * 8 + j) * 64 + lane] = acc[j];
    #pragma unroll
    for (int j = 0; j < 8; ++j) {
        float aa = ba[lane];
        for (int h2 = 0; h2 < 64; ++h2)
            aa = fmaf(__shfl(acc[j], h2), WaeT[h2 * 64 + lane], aa);
        attnPre[((size_t)b * 512 + soct * 8 + j) * 64 + lane] = aa;
    }
}

// ---- attnPre [b][s][h] -> attnPreT [b][h][s] (tile transpose) ------------
__global__ __launch_bounds__(256) void k_attn_transpose(
    const float* __restrict__ attnPre, float* __restrict__ attnPreT)
{
    __shared__ float tile[64][65];
    int b  = blockIdx.x >> 3;        // 0..63
    int s0 = (blockIdx.x & 7) * 64;  // 0..448
    int lane = threadIdx.x & 63;
    int r0   = threadIdx.x >> 6;
    for (int r = r0; r < 64; r += 4)
        tile[r][lane] = attnPre[(size_t)b * 32768 + (size_t)(s0 + r) * 64 + lane];
    __syncthreads();
    for (int r = r0; r < 64; r += 4)
        attnPreT[(size_t)b * 32768 + (size_t)r * 512 + s0 + lane] = tile[lane][r];
}

// ---- attention for one batch b (register-prefetched loads) ---------------
__device__ __forceinline__ void attention_block(
    int b, int tid, int w,
    const float* __restrict__ hcur,     // quad-packed
    const float* __restrict__ Wh_pT, const float* __restrict__ bh_p,
    const float* __restrict__ WahT,  const float* __restrict__ v,
    const float* __restrict__ attnPreT, const float* __restrict__ encProj,
    float* __restrict__ ctxQ, float* smem)
{
    int lane = tid & 63;
    float* hq     = smem;
    float* hWa    = smem + 64;
    float* scores = smem + 128;   // 512
    float* part   = smem + 640;   // 512
    float* red    = smem + 1152;  // 16
    // p1: hq = Wh_p.h + bh_p (h quads prefetched, wave-uniform loads)
    {
        const float4* h4 = (const float4*)hcur;
        float4 hv[16];
        #pragma unroll
        for (int j = 0; j < 16; ++j)
            hv[j] = h4[(w * 16 + j) * 64 + b];
        float p = 0.f;
        #pragma unroll
        for (int j = 0; j < 16; ++j) {
            int q = w * 16 + j;
            p = fmaf(hv[j].x, Wh_pT[(4*q+0) * 64 + lane], p);
            p = fmaf(hv[j].y, Wh_pT[(4*q+1) * 64 + lane], p);
            p = fmaf(hv[j].z, Wh_pT[(4*q+2) * 64 + lane], p);
            p = fmaf(hv[j].w, Wh_pT[(4*q+3) * 64 + lane], p);
        }
        part[w * 64 + lane] = p;
    }
    __syncthreads();
    if (tid < 64) {
        float s = bh_p[tid];
        #pragma unroll
        for (int ww = 0; ww < 8; ++ww) s += part[ww * 64 + tid];
        hq[tid] = s;
    }
    __syncthreads();
    // p2: hWa = Wa_h.hq
    if (tid < 64) {
        float s = 0.f;
        for (int j = 0; j < 64; ++j)
            s = fmaf(hq[j], WahT[j * 64 + tid], s);
        hWa[tid] = s;
    }
    __syncthreads();
    // p3: scores — lane owns s = w*64+lane; 16-deep prefetch rounds
    {
        const float* apT = attnPreT + (size_t)b * 32768 + (w * 64 + lane);
        float acc = 0.f;
        for (int hh = 0; hh < 64; hh += 16) {
            float ap[16];
            #pragma unroll
            for (int j = 0; j < 16; ++j)
                ap[j] = apT[(size_t)(hh + j) * 512];
            #pragma unroll
            for (int j = 0; j < 16; ++j) {
                float e = ftanh(hWa[hh + j] + ap[j]);
                acc = fmaf(v[hh + j], e, acc);
            }
        }
        scores[w * 64 + lane] = acc;
    }
    __syncthreads();
    // softmax over 512
    float sc = scores[tid];
    float m = sc;
    #pragma unroll
    for (int off = 32; off > 0; off >>= 1)
        m = fmaxf(m, __shfl_xor(m, off));
    if (lane == 0) red[w] = m;
    __syncthreads();
    if (tid == 0) {
        float mm = red[0];
        for (int ww = 1; ww < 8; ++ww) mm = fmaxf(mm, red[ww]);
        red[8] = mm;
    }
    __syncthreads();
    float M = red[8];
    float ex = __expf(sc - M);
    scores[tid] = ex;
    float ssum = ex;
    #pragma unroll
    for (int off = 32; off > 0; off >>= 1)
        ssum += __shfl_xor(ssum, off);
    if (lane == 0) red[w] = ssum;
    __syncthreads();
    if (tid == 0) {
        float tt2 = 0.f;
        for (int ww = 0; ww < 8; ++ww) tt2 += red[ww];
        red[8] = 1.0f / tt2;
    }
    __syncthreads();
    float inv = red[8];
    // p5: ctx — wave w covers s in [w*64, w*64+64), 8-deep prefetch rounds
    {
        const float* ep = encProj + ((size_t)b * 512 + w * 64) * 64 + lane;
        float a = 0.f;
        for (int i = 0; i < 64; i += 8) {
            float pv[8];
            #pragma unroll
            for (int j = 0; j < 8; ++j)
                pv[j] = ep[(size_t)(i + j) * 64];
            #pragma unroll
            for (int j = 0; j < 8; ++j)
                a = fmaf(scores[w * 64 + i + j], pv[j], a);
        }
        part[w * 64 + lane] = a;
    }
    __syncthreads();
    if (tid < 64) {
        float s = 0.f;
        #pragma unroll
        for (int ww = 0; ww < 8; ++ww) s += part[ww * 64 + tid];
        coh_store(&ctxQ[(tid >> 2) * 256 + b * 4 + (tid & 3)], s * inv);
    }
}

// ---- decoder LSTM task (fused weights) -----------------------------------
__device__ __forceinline__ void dec_lstm_task(
    int u0, int t, int tid, int w, int lane,
    const float* __restrict__ hc, const float* __restrict__ ctxPrev,
    float* __restrict__ hn, float2& creg,
    const float4* __restrict__ Whh4, const float4* __restrict__ Wh4,
    const float4* __restrict__ Wc4,
    const float* __restrict__ g0, const float* __restrict__ bprime,
    float* smem)
{
    float acc[8];
    #pragma unroll
    for (int r = 0; r < 8; ++r) acc[r] = 0.f;
    if (t == 0) {
        accum_seg_pf<16>(acc, (const float4*)hc, w * 16, Whh4, 128, u0, lane);
        lstm_finish_row(u0, tid, w, acc, creg, g0, hn, smem);
    } else {
        accum_seg_pf<16>(acc, (const float4*)hc, w * 16, Wh4, 128, u0, lane);
        accum_ctx(acc, (const float4*)ctxPrev, Wc4, u0, w, lane);
        lstm_finish_vec(u0, tid, w, acc, creg, bprime, hn, smem);
    }
}

// ---- persistent decoder: 96 steps, ONE barrier each ----------------------
__global__ __launch_bounds__(512, 2) void k_dec_persistent(
    const float* __restrict__ encHend,
    float* __restrict__ dechH,            // [96][quad 32768]
    float* __restrict__ cT,
    const float* __restrict__ Whh,        // t=0 h-part
    const float* __restrict__ Wh,         // t>=1 fused h-part
    const float* __restrict__ Wc,         // ctx part
    const float* __restrict__ g0, const float* __restrict__ bprime,
    const float* __restrict__ Wh_pT, const float* __restrict__ bh_p,
    const float* __restrict__ WahT,  const float* __restrict__ v,
    const float* __restrict__ attnPreT, const float* __restrict__ encProj,
    float* __restrict__ ctxH,             // [96][quad 4096]
    unsigned* flags)
{
    __shared__ float smem[4608];
    int tid = threadIdx.x;
    int lane = tid & 63;
    int w = __builtin_amdgcn_readfirstlane(tid >> 6);
    int bi = blockIdx.x;
    const float4* Whh4 = (const float4*)Whh;
    const float4* Wh4  = (const float4*)Wh;
    const float4* Wc4  = (const float4*)Wc;
    int taskA = -1, taskB = -1;
    if (bi >= 64) { taskA = bi - 64; if (bi < 128) taskB = bi + 128; }
    float2 cA = make_float2(0.f, 0.f), cB = cA;
    if (taskA >= 0 && tid < 64) {
        int u0 = taskA * 2;
        cA.x = cT[u0 * 64 + tid]; cA.y = cT[(u0 + 1) * 64 + tid];
    }
    if (taskB >= 0 && tid < 64) {
        int u0 = taskB * 2;
        cB.x = cT[u0 * 64 + tid]; cB.y = cT[(u0 + 1) * 64 + tid];
    }
    for (int t = 0; t < 96; ++t) {
        bar_wait(flags, (unsigned)t);       // h^{(t)}, ctx^{(t-1)} visible
        const float* hc = t ? dechH + (size_t)(t - 1) * 32768 : encHend;
        const float* cp = t ? ctxH + (size_t)(t - 1) * 4096 : ctxH;
        if (bi < 64) {
            attention_block(bi, tid, w, hc, Wh_pT, bh_p, WahT, v,
                            attnPreT, encProj, ctxH + (size_t)t * 4096, smem);
        } else {
            float* hn = dechH + (size_t)t * 32768;
            dec_lstm_task(taskA * 2, t, tid, w, lane, hc, cp, hn, cA,
                          Whh4, Wh4, Wc4, g0, bprime, smem);
            if (taskB >= 0)
                dec_lstm_task(taskB * 2, t, tid, w, lane, hc, cp, hn, cB,
                              Whh4, Wh4, Wc4, g0, bprime, smem);
        }
        bar_arrive(flags, bi, (unsigned)(t + 1));
    }
}

// ---- post-pass: dout[b][tau] = Wo[255].[h^{(tau+1)}; ctx_tau] + bo[255] --
__global__ __launch_bounds__(256) void k_dout(
    const float* __restrict__ dechH, const float* __restrict__ ctxH,
    const float* __restrict__ Wo, const float* __restrict__ bo,
    float* __restrict__ dout)
{
    __shared__ float part[256];
    int tau = blockIdx.x;            // 0..95
    int tid = threadIdx.x;
    int lane = tid & 63;             // = b
    int w = tid >> 6;                // 0..3, each wave does 144 of 576
    const float* hq = dechH + (size_t)tau * 32768;
    const float* cq = ctxH + (size_t)tau * 4096;
    const float* wrow = Wo + 255 * 576;
    float acc = 0.f;
    for (int i = w * 144; i < w * 144 + 144; ++i) {
        float cat;
        if (i < 512) cat = hq[(i >> 2) * 256 + lane * 4 + (i & 3)];
        else         cat = cq[((i - 512) >> 2) * 256 + lane * 4 + ((i - 512) & 3)];
        acc = fmaf(wrow[i], cat, acc);
    }
    part[w * 64 + lane] = acc;
    __syncthreads();
    if (tid < 64) {
        float s = bo[255];
        #pragma unroll
        for (int ww = 0; ww < 4; ++ww) s += part[ww * 64 + tid];
        dout[tid * 96 + tau] = s;
    }
}

} // namespace

extern "C" void kernel_launch(void* const* d_in, const int* in_sizes, int n_in,
                              void* d_out, int out_size, void* d_ws, size_t ws_size,
                              hipStream_t stream)
{
    (void)in_sizes; (void)n_in; (void)out_size; (void)ws_size;
    const float* input_seq = (const float*)d_in[0];
    const float* h0     = (const float*)d_in[1];
    const float* c0     = (const float*)d_in[2];
    const float* W_ih_e = (const float*)d_in[3];
    const float* W_hh_e = (const float*)d_in[4];
    const float* b_e    = (const float*)d_in[5];
    const float* W_ih_d = (const float*)d_in[6];
    const float* W_hh_d = (const float*)d_in[7];
    const float* b_d    = (const float*)d_in[8];
    const float* We_p   = (const float*)d_in[9];
    const float* be_p   = (const float*)d_in[10];
    const float* Wh_p   = (const float*)d_in[11];
    const float* bh_p   = (const float*)d_in[12];
    const float* Wa     = (const float*)d_in[13];
    const float* ba     = (const float*)d_in[14];
    const float* v      = (const float*)d_in[15];
    const float* Wo     = (const float*)d_in[16];
    const float* bo     = (const float*)d_in[17];
    float* out = (float*)d_out;

    unsigned* encFlags = (unsigned*)d_ws;       // 256 words
    unsigned* decFlags = encFlags + 256;        // 256 words
    float* ws       = (float*)d_ws + 1024;      // 4KB offset
    float* xT       = ws;                       // 8388608 (dead after enc/g0)
    float* encH     = xT + 8388608;             // 513*32768 = 16809984
    float* cT       = encH + 16809984;          // 32768
    float* We_pT    = cT + 32768;               // 32768
    float* Wh_pT    = We_pT + 32768;            // 32768
    float* WahT     = Wh_pT + 32768;            // 4096
    float* WaeT     = WahT + 4096;              // 4096
    float* encProj  = WaeT + 4096;              // 2097152
    float* attnPre  = encProj + 2097152;        // 2097152
    float* dechH    = attnPre + 2097152;        // 96*32768 = 3145728
    float* ctxH     = dechH + 3145728;          // 96*4096 = 393216
    float* Wh       = ctxH + 393216;            // 2048*512 = 1048576
    float* Wc       = Wh + 1048576;             // 2048*64 = 131072
    float* bprime   = Wc + 131072;              // 2048
    float* g0       = bprime + 2048;            // 2048*64 = 131072
    float* attnPreT = xT;                       // aliases dead xT region (2M)

    hipMemsetAsync(d_ws, 0, 4096, stream);      // zero barrier flags
    k_transpose_input<<<2048, 256, 0, stream>>>(input_seq, (float4*)xT);
    k_prep<<<544, 256, 0, stream>>>(We_p, Wh_p, h0, c0, Wa,
                                    We_pT, Wh_pT, encH, cT, WahT, WaeT);
    k_prep_wcomb<<<2048, 256, 0, stream>>>(W_ih_d, W_hh_d, Wo, b_d, bo,
                                           Wh, Wc, bprime);
    k_prep_g0<<<512, 256, 0, stream>>>((const float4*)(xT + (size_t)511 * 16384),
                                       W_ih_d, b_d, g0);
    k_enc_persistent<<<256, 512, 0, stream>>>((const float4*)xT, encH, cT,
                                              W_ih_e, W_hh_e, b_e, encFlags);
    k_proj_attn<<<1024, 256, 0, stream>>>(encH, We_pT, be_p, WaeT, ba,
                                          encProj, attnPre);
    k_attn_transpose<<<512, 256, 0, stream>>>(attnPre, attnPreT);
    k_dec_persistent<<<256, 512, 0, stream>>>(encH + (size_t)512 * 32768,
                                              dechH, cT,
                                              W_hh_d, Wh, Wc, g0, bprime,
                                              Wh_pT, bh_p, WahT, v,
                                              attnPreT, encProj, ctxH,
                                              decFlags);
    k_dout<<<96, 256, 0, stream>>>(dechH, ctxH, Wo, bo, out);
}

// Round 10
// 6982.780 us; speedup vs baseline: 1.5561x; 1.5561x over previous
//
#include <hip/hip_runtime.h>

// Seq2seq LSTM + attention — persistent kernels, contention-free flag barrier.
//
// Round-10 change: LDS-resident attention. encProj/attnPreT are CONSTANT
// across the 96 decoder steps but were re-fetched every step (15.4 MB/step,
// 272 GB/s effective on 64 CUs = 57us/step — the measured decoder time).
// Now: 128 attention blocks (2 per batch, s-halves of 256), each stages its
// 64KB attnPreT-half + 64KB encProj-half into LDS once; split softmax with
// exact combine (publish m, S, ctxsum[64] per half; consumers combine as
// ctx = (e^{m0-M}S0*cs0 + e^{m1-M}S1*cs1-style weighted sum)/den).
// LSTM on blocks 128..255, 2 tasks each. One barrier per step unchanged.
//
// Decoder algebra (round 8): gates_t = W_h.h_t + W_c.ctx_{t-1} + b' (t>=1);
// t=0 uses Whh_d and g0. Pred column via k_dout post-pass (does the combine).
//
// Barrier: arrival = sc1 store to flags[blockIdx]; wait = wave0 polls all 256.
// All cross-block data written once to never-reused addresses via sc1 stores.

namespace {

__device__ __forceinline__ float fsigmoid(float x) {
    return 1.0f / (1.0f + __expf(-x));
}
__device__ __forceinline__ float ftanh(float x) {
    float e = __expf(2.0f * x);
    return 1.0f - 2.0f / (e + 1.0f);
}

__device__ __forceinline__ void coh_store(float* p, float v) {
    __hip_atomic_store(p, v, __ATOMIC_RELAXED, __HIP_MEMORY_SCOPE_AGENT);
}
__device__ __forceinline__ void coh_store2(float* p, float2 v) {
    union { float2 f; unsigned long long u; } cv; cv.f = v;
    __hip_atomic_store((unsigned long long*)p, cv.u,
                       __ATOMIC_RELAXED, __HIP_MEMORY_SCOPE_AGENT);
}

// ---- contention-free barrier ---------------------------------------------
__device__ __forceinline__ void bar_arrive(unsigned* flags, int bi, unsigned val) {
    if (threadIdx.x < 64) {
        asm volatile("s_waitcnt vmcnt(0)" ::: "memory");
        if (threadIdx.x == 0)
            __hip_atomic_store(&flags[bi], val, __ATOMIC_RELAXED, __HIP_MEMORY_SCOPE_AGENT);
    }
}
__device__ __forceinline__ void bar_wait(const unsigned* flags, unsigned epoch) {
    if (threadIdx.x < 64) {
        const unsigned* f = flags + threadIdx.x * 4;
        for (;;) {
            unsigned a = __hip_atomic_load(f + 0, __ATOMIC_RELAXED, __HIP_MEMORY_SCOPE_AGENT);
            unsigned b = __hip_atomic_load(f + 1, __ATOMIC_RELAXED, __HIP_MEMORY_SCOPE_AGENT);
            unsigned c = __hip_atomic_load(f + 2, __ATOMIC_RELAXED, __HIP_MEMORY_SCOPE_AGENT);
            unsigned d = __hip_atomic_load(f + 3, __ATOMIC_RELAXED, __HIP_MEMORY_SCOPE_AGENT);
            int ok = (a >= epoch) && (b >= epoch) && (c >= epoch) && (d >= epoch);
            if (__all(ok)) break;
            __builtin_amdgcn_s_sleep(1);
        }
    }
    __syncthreads();
}

// ---- transpose input_seq (B,S,F) -> quad layout [s][f/4][b][4] -----------
__global__ __launch_bounds__(256) void k_transpose_input(
    const float* __restrict__ in, float4* __restrict__ xQ)
{
    __shared__ float tile[64][65];
    int s  = blockIdx.x >> 2;
    int f0 = (blockIdx.x & 3) * 64;
    int lane = threadIdx.x & 63;
    int r0   = threadIdx.x >> 6;
    for (int r = r0; r < 64; r += 4)
        tile[r][lane] = in[(size_t)r * (512 * 256) + s * 256 + f0 + lane];
    __syncthreads();
    for (int q = r0; q < 16; q += 4) {
        float4 vv = make_float4(tile[lane][4*q], tile[lane][4*q+1],
                                tile[lane][4*q+2], tile[lane][4*q+3]);
        xQ[((size_t)s * 64 + (f0 >> 2) + q) * 64 + lane] = vv;
    }
}

// ---- small weight/state transposes; encH slot0 quad-packed ---------------
__global__ __launch_bounds__(256) void k_prep(
    const float* __restrict__ We_p, const float* __restrict__ Wh_p,
    const float* __restrict__ h0,   const float* __restrict__ c0,
    const float* __restrict__ Wa,
    float* __restrict__ We_pT, float* __restrict__ Wh_pT,
    float* __restrict__ encH0, float* __restrict__ cT,
    float* __restrict__ WahT,  float* __restrict__ WaeT)
{
    int idx = blockIdx.x * blockDim.x + threadIdx.x;
    const int total = 32768 * 4 + 4096 * 2;
    for (; idx < total; idx += gridDim.x * blockDim.x) {
        if (idx < 32768) {
            int u = idx >> 6, h = idx & 63;
            We_pT[idx] = We_p[h * 512 + u];
        } else if (idx < 65536) {
            int i2 = idx - 32768; int k = i2 >> 6, i = i2 & 63;
            Wh_pT[i2] = Wh_p[i * 512 + k];
        } else if (idx < 98304) {
            int i2 = idx - 65536; int u = i2 >> 6, b = i2 & 63;
            encH0[(u >> 2) * 256 + b * 4 + (u & 3)] = h0[b * 512 + u];
        } else if (idx < 131072) {
            int i2 = idx - 98304; int u = i2 >> 6, b = i2 & 63;
            cT[i2] = c0[b * 512 + u];
        } else if (idx < 135168) {
            int i2 = idx - 131072; int j = i2 >> 6, i = i2 & 63;
            WahT[i2] = Wa[i * 128 + j];
        } else {
            int i2 = idx - 135168; int h2 = i2 >> 6, h = i2 & 63;
            WaeT[i2] = Wa[h * 128 + 64 + h2];
        }
    }
}

// ---- W_h = Wih_d.Wo[:, :512] + Whh_d ; W_c = Wih_d.Wo[:, 512:] ; b' ------
__global__ __launch_bounds__(256) void k_prep_wcomb(
    const float* __restrict__ Wih, const float* __restrict__ Whh,
    const float* __restrict__ Wo,  const float* __restrict__ bd,
    const float* __restrict__ bo,
    float* __restrict__ Wh, float* __restrict__ Wc, float* __restrict__ bprime)
{
    int r = blockIdx.x;          // 0..2047
    for (int j = threadIdx.x; j < 576; j += 256) {
        float acc = 0.f;
        for (int f = 0; f < 256; ++f)
            acc = fmaf(Wih[r * 256 + f], Wo[f * 576 + j], acc);
        if (j < 512) Wh[(size_t)r * 512 + j] = acc + Whh[(size_t)r * 512 + j];
        else         Wc[(size_t)r * 64 + (j - 512)] = acc;
    }
    if (threadIdx.x == 0) {
        float s = bd[r];
        for (int f = 0; f < 256; ++f)
            s = fmaf(Wih[r * 256 + f], bo[f], s);
        bprime[r] = s;
    }
}

// ---- g0[r][b] = Wih_d . x_last + b_d -------------------------------------
__global__ __launch_bounds__(256) void k_prep_g0(
    const float4* __restrict__ xQlast, const float* __restrict__ Wih,
    const float* __restrict__ bd, float* __restrict__ g0)
{
    int r = blockIdx.x * 4 + ((int)threadIdx.x >> 6);
    int lane = threadIdx.x & 63;
    const float4* Wih4 = (const float4*)Wih;
    float acc = bd[r];
    for (int q = 0; q < 64; ++q) {
        float4 a  = xQlast[q * 64 + lane];
        float4 wv = Wih4[(size_t)r * 64 + q];
        acc = fmaf(a.x, wv.x, acc); acc = fmaf(a.y, wv.y, acc);
        acc = fmaf(a.z, wv.z, acc); acc = fmaf(a.w, wv.w, acc);
    }
    g0[(size_t)r * 64 + lane] = acc;
}

// ---- gate-GEMM accumulation, register-prefetched (NQ = 8 or 16) ----------
template<int NQ>
__device__ __forceinline__ void accum_seg_pf(
    float acc[8], const float4* __restrict__ actQ, int qb,
    const float4* __restrict__ W4, int wstride, int u0, int lane)
{
    float4 a[NQ];
    #pragma unroll
    for (int q = 0; q < NQ; ++q)
        a[q] = actQ[(qb + q) * 64 + lane];
    #pragma unroll
    for (int q = 0; q < NQ; ++q) {
        #pragma unroll
        for (int uu = 0; uu < 2; ++uu)
            #pragma unroll
            for (int g = 0; g < 4; ++g) {
                float4 wv = W4[(size_t)(g * 512 + u0 + uu) * wstride + (qb + q)];
                float& A = acc[uu * 4 + g];
                A = fmaf(a[q].x, wv.x, A); A = fmaf(a[q].y, wv.y, A);
                A = fmaf(a[q].z, wv.z, A); A = fmaf(a[q].w, wv.w, A);
            }
    }
}

// ---- ctx-part accumulation from pre-combined register quads --------------
__device__ __forceinline__ void accum_ctx_reg(
    float acc[8], float4 c0, float4 c1,
    const float4* __restrict__ Wc4, int u0, int w)
{
    #pragma unroll
    for (int uu = 0; uu < 2; ++uu)
        #pragma unroll
        for (int g = 0; g < 4; ++g) {
            float4 w0 = Wc4[(size_t)(g * 512 + u0 + uu) * 16 + w * 2 + 0];
            float4 w1 = Wc4[(size_t)(g * 512 + u0 + uu) * 16 + w * 2 + 1];
            float& A = acc[uu * 4 + g];
            A = fmaf(c0.x, w0.x, A); A = fmaf(c0.y, w0.y, A);
            A = fmaf(c0.z, w0.z, A); A = fmaf(c0.w, w0.w, A);
            A = fmaf(c1.x, w1.x, A); A = fmaf(c1.y, w1.y, A);
            A = fmaf(c1.z, w1.z, A); A = fmaf(c1.w, w1.w, A);
        }
}

// ---- finish variant 1: additive = per-row vector (bias / b') -------------
__device__ __forceinline__ void lstm_finish_vec(
    int u0, int tid, int w, float acc[8], float2& creg,
    const float* __restrict__ addVec, float* __restrict__ houtSlot, float* smem)
{
    int lane = tid & 63;
    float* part = smem;          // [8][8][64]
    float* gsum = smem + 4096;   // [8][64]
    #pragma unroll
    for (int r = 0; r < 8; ++r)
        part[(w * 8 + r) * 64 + lane] = acc[r];
    __syncthreads();
    {
        int b = tid & 63, r = tid >> 6;
        float s = 0.f;
        #pragma unroll
        for (int ww = 0; ww < 8; ++ww)
            s += part[(ww * 8 + r) * 64 + b];
        gsum[r * 64 + b] = s;
    }
    __syncthreads();
    if (tid < 64) {
        int b = tid;
        float cc[2] = {creg.x, creg.y};
        float hv[2];
        #pragma unroll
        for (int uu = 0; uu < 2; ++uu) {
            int u = u0 + uu;
            float gi = gsum[(uu*4+0)*64 + b] + addVec[u];
            float gf = gsum[(uu*4+1)*64 + b] + addVec[512 + u];
            float gg = gsum[(uu*4+2)*64 + b] + addVec[1024 + u];
            float go = gsum[(uu*4+3)*64 + b] + addVec[1536 + u];
            float si = fsigmoid(gi), sf = fsigmoid(gf), so = fsigmoid(go);
            float tg = ftanh(gg);
            float cn = sf * cc[uu] + si * tg;
            cc[uu] = cn;
            hv[uu] = so * ftanh(cn);
        }
        creg = make_float2(cc[0], cc[1]);
        coh_store2(houtSlot + (u0 >> 2) * 256 + b * 4 + (u0 & 3),
                   make_float2(hv[0], hv[1]));
    }
}

// ---- finish variant 2: additive = row x batch buffer (g0) ----------------
__device__ __forceinline__ void lstm_finish_row(
    int u0, int tid, int w, float acc[8], float2& creg,
    const float* __restrict__ addRowB, float* __restrict__ houtSlot, float* smem)
{
    int lane = tid & 63;
    float* part = smem;
    float* gsum = smem + 4096;
    #pragma unroll
    for (int r = 0; r < 8; ++r)
        part[(w * 8 + r) * 64 + lane] = acc[r];
    __syncthreads();
    {
        int b = tid & 63, r = tid >> 6;
        float s = 0.f;
        #pragma unroll
        for (int ww = 0; ww < 8; ++ww)
            s += part[(ww * 8 + r) * 64 + b];
        gsum[r * 64 + b] = s;
    }
    __syncthreads();
    if (tid < 64) {
        int b = tid;
        float cc[2] = {creg.x, creg.y};
        float hv[2];
        #pragma unroll
        for (int uu = 0; uu < 2; ++uu) {
            int u = u0 + uu;
            float gi = gsum[(uu*4+0)*64 + b] + addRowB[(size_t)(0 * 512 + u) * 64 + b];
            float gf = gsum[(uu*4+1)*64 + b] + addRowB[(size_t)(1 * 512 + u) * 64 + b];
            float gg = gsum[(uu*4+2)*64 + b] + addRowB[(size_t)(2 * 512 + u) * 64 + b];
            float go = gsum[(uu*4+3)*64 + b] + addRowB[(size_t)(3 * 512 + u) * 64 + b];
            float si = fsigmoid(gi), sf = fsigmoid(gf), so = fsigmoid(go);
            float tg = ftanh(gg);
            float cn = sf * cc[uu] + si * tg;
            cc[uu] = cn;
            hv[uu] = so * ftanh(cn);
        }
        creg = make_float2(cc[0], cc[1]);
        coh_store2(houtSlot + (u0 >> 2) * 256 + b * 4 + (u0 & 3),
                   make_float2(hv[0], hv[1]));
    }
}

// ---- persistent encoder: overlap x-part(t+1) with barrier ----------------
__global__ __launch_bounds__(512, 2) void k_enc_persistent(
    const float4* __restrict__ xQ, float* __restrict__ encH,
    float* __restrict__ cT,
    const float* __restrict__ Wih, const float* __restrict__ Whh,
    const float* __restrict__ bias, unsigned* flags)
{
    __shared__ float smem[4608];
    int tid = threadIdx.x;
    int lane = tid & 63;
    int w = __builtin_amdgcn_readfirstlane(tid >> 6);
    int bi = blockIdx.x;
    int u0 = bi * 2;
    const float4* Wih4 = (const float4*)Wih;
    const float4* Whh4 = (const float4*)Whh;
    float2 creg = make_float2(0.f, 0.f);
    if (tid < 64) { creg.x = cT[u0 * 64 + tid]; creg.y = cT[(u0 + 1) * 64 + tid]; }
    float acc[8];
    #pragma unroll
    for (int r = 0; r < 8; ++r) acc[r] = 0.f;
    accum_seg_pf<8>(acc, xQ, w * 8, Wih4, 64, u0, lane);       // x-part t=0
    for (int t = 0; t < 512; ++t) {
        bar_wait(flags, (unsigned)t);                           // h[t] ready
        accum_seg_pf<16>(acc, (const float4*)(encH + (size_t)t * 32768),
                         w * 16, Whh4, 128, u0, lane);
        lstm_finish_vec(u0, tid, w, acc, creg, bias,
                        encH + (size_t)(t + 1) * 32768, smem);
        bar_arrive(flags, bi, (unsigned)(t + 1));
        #pragma unroll
        for (int r = 0; r < 8; ++r) acc[r] = 0.f;
        if (t + 1 < 512)   // x-part t+1 under barrier; step stride = 4096 float4
            accum_seg_pf<8>(acc, xQ + (size_t)(t + 1) * 4096, w * 8, Wih4, 64, u0, lane);
    }
    if (tid < 64) { cT[u0 * 64 + tid] = creg.x; cT[(u0 + 1) * 64 + tid] = creg.y; }
}

// ---- enc_proj + enc_attn (ba folded), round-5 form -----------------------
__global__ __launch_bounds__(256) void k_proj_attn(
    const float* __restrict__ encH,  const float* __restrict__ We_pT,
    const float* __restrict__ be_p,  const float* __restrict__ WaeT,
    const float* __restrict__ ba,
    float* __restrict__ encProj, float* __restrict__ attnPre)
{
    int lane = threadIdx.x & 63;
    int w    = __builtin_amdgcn_readfirstlane((int)threadIdx.x >> 6);
    int wid  = blockIdx.x * 4 + w;
    int b    = wid >> 6;
    int soct = wid & 63;
    float acc[8];
    float bep = be_p[lane];
    #pragma unroll
    for (int j = 0; j < 8; ++j) acc[j] = bep;
    #pragma unroll 2
    for (int q = 0; q < 128; ++q) {
        float w0 = We_pT[(4*q+0) * 64 + lane];
        float w1 = We_pT[(4*q+1) * 64 + lane];
        float w2 = We_pT[(4*q+2) * 64 + lane];
        float w3 = We_pT[(4*q+3) * 64 + lane];
        #pragma unroll
        for (int j = 0; j < 8; ++j) {
            const float4* hb4 = (const float4*)(encH + (size_t)(soct*8 + j + 1) * 32768);
            float4 hv = hb4[q * 64 + b];
            acc[j] = fmaf(hv.x, w0, acc[j]); acc[j] = fmaf(hv.y, w1, acc[j]);
            acc[j] = fmaf(hv.z, w2, acc[j]); acc[j] = fmaf(hv.w, w3, acc[j]);
        }
    }
    #pragma unroll
    for (int j = 0; j < 8; ++j)
        encProj[((size_t)b * 512 + soct * 8 + j) * 64 + lane] = acc[j];
    #pragma unroll
    for (int j = 0; j < 8; ++j) {
        float aa = ba[lane];
        for (int h2 = 0; h2 < 64; ++h2)
            aa = fmaf(__shfl(acc[j], h2), WaeT[h2 * 64 + lane], aa);
        attnPre[((size_t)b * 512 + soct * 8 + j) * 64 + lane] = aa;
    }
}

// ---- attnPre [b][s][h] -> attnPreT [b][h][s] (tile transpose) ------------
__global__ __launch_bounds__(256) void k_attn_transpose(
    const float* __restrict__ attnPre, float* __restrict__ attnPreT)
{
    __shared__ float tile[64][65];
    int b  = blockIdx.x >> 3;        // 0..63
    int s0 = (blockIdx.x & 7) * 64;  // 0..448
    int lane = threadIdx.x & 63;
    int r0   = threadIdx.x >> 6;
    for (int r = r0; r < 64; r += 4)
        tile[r][lane] = attnPre[(size_t)b * 32768 + (size_t)(s0 + r) * 64 + lane];
    __syncthreads();
    for (int r = r0; r < 64; r += 4)
        attnPreT[(size_t)b * 32768 + (size_t)r * 512 + s0 + lane] = tile[lane][r];
}

// ---- attention HALF for batch b (LDS-resident ap/ep slices) --------------
// Publishes m, S, ctxsum[64] (raw e^{sc-m} weighted) for exact combine.
__device__ __forceinline__ void attention_half(
    int b, int tid, int w, int lane,
    const float* __restrict__ hcur,     // quad-packed h (full)
    const float* __restrict__ Wh_pT, const float* __restrict__ bh_p,
    const float* __restrict__ WahT,  const float* __restrict__ v,
    const float* __restrict__ apL,      // LDS [64][256]
    const float* __restrict__ epL,      // LDS [256][64]
    float* __restrict__ ctxsumOut,      // [h2>>2][b][4] quad-packed (4096)
    float* __restrict__ mSOut,          // [0..63]=m, [64..127]=S per b
    float* smem)
{
    float* hq  = smem;          // 64
    float* hWa = smem + 64;     // 64
    float* sc  = smem + 128;    // 256
    float* part = smem + 384;   // 512
    float* red  = smem + 896;   // 16
    // p1: hq = Wh_p.h + bh_p (broadcast h quads)
    {
        const float4* h4 = (const float4*)hcur;
        float4 hv[16];
        #pragma unroll
        for (int j = 0; j < 16; ++j)
            hv[j] = h4[(w * 16 + j) * 64 + b];
        float p = 0.f;
        #pragma unroll
        for (int j = 0; j < 16; ++j) {
            int q = w * 16 + j;
            p = fmaf(hv[j].x, Wh_pT[(4*q+0) * 64 + lane], p);
            p = fmaf(hv[j].y, Wh_pT[(4*q+1) * 64 + lane], p);
            p = fmaf(hv[j].z, Wh_pT[(4*q+2) * 64 + lane], p);
            p = fmaf(hv[j].w, Wh_pT[(4*q+3) * 64 + lane], p);
        }
        part[w * 64 + lane] = p;
    }
    __syncthreads();
    if (tid < 64) {
        float s = bh_p[tid];
        #pragma unroll
        for (int ww = 0; ww < 8; ++ww) s += part[ww * 64 + tid];
        hq[tid] = s;
    }
    __syncthreads();
    // p2: hWa = Wa_h.hq
    if (tid < 64) {
        float s = 0.f;
        for (int j = 0; j < 64; ++j)
            s = fmaf(hq[j], WahT[j * 64 + tid], s);
        hWa[tid] = s;
    }
    __syncthreads();
    // p3: scores from LDS; thread = (hhalf, s'), 32 h each
    {
        int sp  = tid & 255;
        int hh0 = (tid >> 8) * 32;
        float acc = 0.f;
        for (int j = 0; j < 32; ++j) {
            int h = hh0 + j;
            float e = ftanh(hWa[h] + apL[h * 256 + sp]);
            acc = fmaf(v[h], e, acc);
        }
        part[tid] = acc;
    }
    __syncthreads();
    if (tid < 256)
        sc[tid] = part[tid] + part[256 + tid];
    __syncthreads();
    // p4: partial softmax over 256 (waves 0..3)
    if (tid < 256) {
        float x = sc[tid];
        float m = x;
        #pragma unroll
        for (int off = 32; off > 0; off >>= 1)
            m = fmaxf(m, __shfl_xor(m, off));
        if (lane == 0) red[w] = m;
    }
    __syncthreads();
    if (tid == 0)
        red[8] = fmaxf(fmaxf(red[0], red[1]), fmaxf(red[2], red[3]));
    __syncthreads();
    float M = red[8];
    if (tid < 256) {
        float e = __expf(sc[tid] - M);
        sc[tid] = e;
        float s = e;
        #pragma unroll
        for (int off = 32; off > 0; off >>= 1)
            s += __shfl_xor(s, off);
        if (lane == 0) red[w] = s;
    }
    __syncthreads();
    if (tid == 0)
        red[9] = ((red[0] + red[1]) + (red[2] + red[3]));
    __syncthreads();
    // p5: ctxsum[h2] = sum_s' e_s' * epL[s'][h2]; wave w covers 32 s'
    {
        float a = 0.f;
        for (int i = 0; i < 32; ++i) {
            int sp2 = w * 32 + i;
            a = fmaf(sc[sp2], epL[sp2 * 64 + lane], a);
        }
        part[w * 64 + lane] = a;
    }
    __syncthreads();
    if (tid < 64) {
        float s = 0.f;
        #pragma unroll
        for (int ww = 0; ww < 8; ++ww) s += part[ww * 64 + tid];
        coh_store(&ctxsumOut[(tid >> 2) * 256 + b * 4 + (tid & 3)], s);
    }
    if (tid == 0) {
        coh_store(&mSOut[b], M);
        coh_store(&mSOut[64 + b], red[9]);
    }
    __syncthreads();
}

// ---- combined ctx quads for a wave (lane = b) ----------------------------
__device__ __forceinline__ void load_ctx_quads(
    int t, int w, int lane,
    const float* __restrict__ ctxsumH, const float* __restrict__ mSbuf,
    float4& c0, float4& c1)
{
    const float* mS = mSbuf + (size_t)(t - 1) * 256;
    float m0 = mS[lane],       S0 = mS[64 + lane];
    float m1 = mS[128 + lane], S1 = mS[192 + lane];
    float M  = fmaxf(m0, m1);
    float e0 = __expf(m0 - M), e1 = __expf(m1 - M);
    float inv = 1.0f / (e0 * S0 + e1 * S1);
    e0 *= inv; e1 *= inv;
    const float4* a0 = (const float4*)(ctxsumH + (size_t)(t - 1) * 8192);
    const float4* a1 = (const float4*)(ctxsumH + (size_t)(t - 1) * 8192 + 4096);
    float4 x0 = a0[(w * 2 + 0) * 64 + lane];
    float4 y0 = a1[(w * 2 + 0) * 64 + lane];
    float4 x1 = a0[(w * 2 + 1) * 64 + lane];
    float4 y1 = a1[(w * 2 + 1) * 64 + lane];
    c0 = make_float4(e0 * x0.x + e1 * y0.x, e0 * x0.y + e1 * y0.y,
                     e0 * x0.z + e1 * y0.z, e0 * x0.w + e1 * y0.w);
    c1 = make_float4(e0 * x1.x + e1 * y1.x, e0 * x1.y + e1 * y1.y,
                     e0 * x1.z + e1 * y1.z, e0 * x1.w + e1 * y1.w);
}

// ---- persistent decoder: 128 attn-half blocks + 128 LSTM blocks ----------
extern __shared__ float dynsmem[];
__global__ __launch_bounds__(512) void k_dec_persistent(
    const float* __restrict__ encHend,
    float* __restrict__ dechH,            // [96][quad 32768]
    float* __restrict__ cT,
    const float* __restrict__ Whh,        // t=0 h-part
    const float* __restrict__ Wh,         // t>=1 fused h-part
    const float* __restrict__ Wc,         // ctx part
    const float* __restrict__ g0, const float* __restrict__ bprime,
    const float* __restrict__ Wh_pT, const float* __restrict__ bh_p,
    const float* __restrict__ WahT,  const float* __restrict__ v,
    const float* __restrict__ attnPreT, const float* __restrict__ encProj,
    float* __restrict__ ctxsumH,          // [96][2][4096]
    float* __restrict__ mSbuf,            // [96][256]
    unsigned* flags)
{
    float* smem = dynsmem;                // 4608 floats scratch
    float* apL  = dynsmem + 4608;         // 16384: [h][s']
    float* epL  = apL + 16384;            // 16384: [s'][h2]
    int tid = threadIdx.x;
    int lane = tid & 63;
    int w = __builtin_amdgcn_readfirstlane(tid >> 6);
    int bi = blockIdx.x;
    if (bi < 128) {
        int b = bi & 63, half = bi >> 6;
        {   // stage attnPreT half: rows h, 256 floats each
            const float4* src = (const float4*)(attnPreT + (size_t)b * 32768 + half * 256);
            float4* dst = (float4*)apL;
            for (int i = tid; i < 4096; i += 512) {
                int h = i >> 6, qc = i & 63;
                dst[i] = src[(size_t)h * 128 + qc];
            }
        }
        {   // stage encProj half: contiguous 16384 floats
            const float4* src = (const float4*)(encProj + ((size_t)b * 512 + half * 256) * 64);
            float4* dst = (float4*)epL;
            for (int i = tid; i < 4096; i += 512)
                dst[i] = src[i];
        }
        __syncthreads();
        for (int t = 0; t < 96; ++t) {
            bar_wait(flags, (unsigned)t);
            const float* hc = t ? dechH + (size_t)(t - 1) * 32768 : encHend;
            attention_half(b, tid, w, lane, hc, Wh_pT, bh_p, WahT, v,
                           apL, epL,
                           ctxsumH + (size_t)t * 8192 + half * 4096,
                           mSbuf + (size_t)t * 256 + half * 128, smem);
            bar_arrive(flags, bi, (unsigned)(t + 1));
        }
    } else {
        int u0A = (bi - 128) * 2;         // tasks bi-128 and bi (u0 + 256)
        int u0B = u0A + 256;
        const float4* Whh4 = (const float4*)Whh;
        const float4* Wh4  = (const float4*)Wh;
        const float4* Wc4  = (const float4*)Wc;
        float2 cA = make_float2(0.f, 0.f), cB = cA;
        if (tid < 64) {
            cA.x = cT[u0A * 64 + tid]; cA.y = cT[(u0A + 1) * 64 + tid];
            cB.x = cT[u0B * 64 + tid]; cB.y = cT[(u0B + 1) * 64 + tid];
        }
        for (int t = 0; t < 96; ++t) {
            bar_wait(flags, (unsigned)t);
            const float* hc = t ? dechH + (size_t)(t - 1) * 32768 : encHend;
            float* hn = dechH + (size_t)t * 32768;
            float acc[8];
            if (t == 0) {
                #pragma unroll
                for (int r = 0; r < 8; ++r) acc[r] = 0.f;
                accum_seg_pf<16>(acc, (const float4*)hc, w * 16, Whh4, 128, u0A, lane);
                lstm_finish_row(u0A, tid, w, acc, cA, g0, hn, smem);
                #pragma unroll
                for (int r = 0; r < 8; ++r) acc[r] = 0.f;
                accum_seg_pf<16>(acc, (const float4*)hc, w * 16, Whh4, 128, u0B, lane);
                lstm_finish_row(u0B, tid, w, acc, cB, g0, hn, smem);
            } else {
                float4 cq0, cq1;
                load_ctx_quads(t, w, lane, ctxsumH, mSbuf, cq0, cq1);
                #pragma unroll
                for (int r = 0; r < 8; ++r) acc[r] = 0.f;
                accum_seg_pf<16>(acc, (const float4*)hc, w * 16, Wh4, 128, u0A, lane);
                accum_ctx_reg(acc, cq0, cq1, Wc4, u0A, w);
                lstm_finish_vec(u0A, tid, w, acc, cA, bprime, hn, smem);
                #pragma unroll
                for (int r = 0; r < 8; ++r) acc[r] = 0.f;
                accum_seg_pf<16>(acc, (const float4*)hc, w * 16, Wh4, 128, u0B, lane);
                accum_ctx_reg(acc, cq0, cq1, Wc4, u0B, w);
                lstm_finish_vec(u0B, tid, w, acc, cB, bprime, hn, smem);
            }
            bar_arrive(flags, bi, (unsigned)(t + 1));
        }
    }
}

// ---- post-pass: dout[b][tau] = Wo[255].[h^{(tau+1)}; ctx_tau] + bo[255] --
__global__ __launch_bounds__(256) void k_dout(
    const float* __restrict__ dechH,
    const float* __restrict__ ctxsumH, const float* __restrict__ mSbuf,
    const float* __restrict__ Wo, const float* __restrict__ bo,
    float* __restrict__ dout)
{
    __shared__ float part[256];
    int tau = blockIdx.x;            // 0..95
    int tid = threadIdx.x;
    int lane = tid & 63;             // = b
    int w = tid >> 6;                // 0..3
    const float* hq = dechH + (size_t)tau * 32768;
    const float* wrow = Wo + 255 * 576;
    float acc = 0.f;
    for (int i = w * 128; i < w * 128 + 128; ++i)
        acc = fmaf(wrow[i], hq[(i >> 2) * 256 + lane * 4 + (i & 3)], acc);
    part[w * 64 + lane] = acc;
    __syncthreads();
    if (tid < 64) {
        int b = tid;
        const float* mS = mSbuf + (size_t)tau * 256;
        float m0 = mS[b],       S0 = mS[64 + b];
        float m1 = mS[128 + b], S1 = mS[192 + b];
        float M  = fmaxf(m0, m1);
        float e0 = __expf(m0 - M), e1 = __expf(m1 - M);
        float inv = 1.0f / (e0 * S0 + e1 * S1);
        e0 *= inv; e1 *= inv;
        const float* cs0 = ctxsumH + (size_t)tau * 8192;
        const float* cs1 = cs0 + 4096;
        float a2 = bo[255];
        for (int h2 = 0; h2 < 64; ++h2) {
            int idx = (h2 >> 2) * 256 + b * 4 + (h2 & 3);
            a2 = fmaf(wrow[512 + h2], e0 * cs0[idx] + e1 * cs1[idx], a2);
        }
        float s = a2 + part[b] + part[64 + b] + part[128 + b] + part[192 + b];
        dout[b * 96 + tau] = s;
    }
}

} // namespace

extern "C" void kernel_launch(void* const* d_in, const int* in_sizes, int n_in,
                              void* d_out, int out_size, void* d_ws, size_t ws_size,
                              hipStream_t stream)
{
    (void)in_sizes; (void)n_in; (void)out_size; (void)ws_size;
    const float* input_seq = (const float*)d_in[0];
    const float* h0     = (const float*)d_in[1];
    const float* c0     = (const float*)d_in[2];
    const float* W_ih_e = (const float*)d_in[3];
    const float* W_hh_e = (const float*)d_in[4];
    const float* b_e    = (const float*)d_in[5];
    const float* W_ih_d = (const float*)d_in[6];
    const float* W_hh_d = (const float*)d_in[7];
    const float* b_d    = (const float*)d_in[8];
    const float* We_p   = (const float*)d_in[9];
    const float* be_p   = (const float*)d_in[10];
    const float* Wh_p   = (const float*)d_in[11];
    const float* bh_p   = (const float*)d_in[12];
    const float* Wa     = (const float*)d_in[13];
    const float* ba     = (const float*)d_in[14];
    const float* v      = (const float*)d_in[15];
    const float* Wo     = (const float*)d_in[16];
    const float* bo     = (const float*)d_in[17];
    float* out = (float*)d_out;

    unsigned* encFlags = (unsigned*)d_ws;       // 256 words
    unsigned* decFlags = encFlags + 256;        // 256 words
    float* ws       = (float*)d_ws + 1024;      // 4KB offset
    float* xT       = ws;                       // 8388608 (dead after enc/g0)
    float* encH     = xT + 8388608;             // 513*32768 = 16809984
    float* cT       = encH + 16809984;          // 32768
    float* We_pT    = cT + 32768;               // 32768
    float* Wh_pT    = We_pT + 32768;            // 32768
    float* WahT     = Wh_pT + 32768;            // 4096
    float* WaeT     = WahT + 4096;              // 4096
    float* encProj  = WaeT + 4096;              // 2097152
    float* attnPre  = encProj + 2097152;        // 2097152
    float* dechH    = attnPre + 2097152;        // 96*32768 = 3145728
    float* ctxsumH  = dechH + 3145728;          // 96*2*4096 = 786432
    float* mSbuf    = ctxsumH + 786432;         // 96*256 = 24576
    float* Wh       = mSbuf + 24576;            // 2048*512 = 1048576
    float* Wc       = Wh + 1048576;             // 2048*64 = 131072
    float* bprime   = Wc + 131072;              // 2048
    float* g0       = bprime + 2048;            // 2048*64 = 131072
    float* attnPreT = xT;                       // aliases dead xT region (2M)

    // allow >64KB dynamic LDS for the decoder (149504 B); ignore errors
    (void)hipFuncSetAttribute((const void*)k_dec_persistent,
                              hipFuncAttributeMaxDynamicSharedMemorySize, 149504);

    hipMemsetAsync(d_ws, 0, 4096, stream);      // zero barrier flags
    k_transpose_input<<<2048, 256, 0, stream>>>(input_seq, (float4*)xT);
    k_prep<<<544, 256, 0, stream>>>(We_p, Wh_p, h0, c0, Wa,
                                    We_pT, Wh_pT, encH, cT, WahT, WaeT);
    k_prep_wcomb<<<2048, 256, 0, stream>>>(W_ih_d, W_hh_d, Wo, b_d, bo,
                                           Wh, Wc, bprime);
    k_prep_g0<<<512, 256, 0, stream>>>((const float4*)(xT + (size_t)511 * 16384),
                                       W_ih_d, b_d, g0);
    k_enc_persistent<<<256, 512, 0, stream>>>((const float4*)xT, encH, cT,
                                              W_ih_e, W_hh_e, b_e, encFlags);
    k_proj_attn<<<1024, 256, 0, stream>>>(encH, We_pT, be_p, WaeT, ba,
                                          encProj, attnPre);
    k_attn_transpose<<<512, 256, 0, stream>>>(attnPre, attnPreT);
    k_dec_persistent<<<256, 512, 149504, stream>>>(encH + (size_t)512 * 32768,
                                                   dechH, cT,
                                                   W_hh_d, Wh, Wc, g0, bprime,
                                                   Wh_pT, bh_p, WahT, v,
                                                   attnPreT, encProj,
                                                   ctxsumH, mSbuf, decFlags);
    k_dout<<<96, 256, 0, stream>>>(dechH, ctxsumH, mSbuf, Wo, bo, out);
}

// Round 11
// 6840.514 us; speedup vs baseline: 1.5885x; 1.0208x over previous
//
#include <hip/hip_runtime.h>

// Seq2seq LSTM + attention — persistent kernels, TWO-LEVEL gen barrier.
//
// Round-11 change: barrier contention fix. Evidence: enc (r8 VGPR20/VALU32%)
// and r10 (VGPR76/VALU69%) both ~10us/step; dec ~13us/step with LDS-resident
// compute => ~7us/step is barrier. Old wait: every block's wave0 polls all
// 256 flags (1KB uncached L3 reads/block/iter, 16 hot lines x 256 blocks).
// New: block 0 alone aggregates flags -> publishes single `gen` word; all
// others poll gen with ONE thread (s_sleep(4)). ~4000x less poll traffic,
// +1 hop latency.
//
// Everything else identical to round 10 (passed, absmax 0.0):
// LDS-resident split attention, fused decoder weights, quad layouts,
// fresh-address sc1 publication scheme.

namespace {

__device__ __forceinline__ float fsigmoid(float x) {
    return 1.0f / (1.0f + __expf(-x));
}
__device__ __forceinline__ float ftanh(float x) {
    float e = __expf(2.0f * x);
    return 1.0f - 2.0f / (e + 1.0f);
}

__device__ __forceinline__ void coh_store(float* p, float v) {
    __hip_atomic_store(p, v, __ATOMIC_RELAXED, __HIP_MEMORY_SCOPE_AGENT);
}
__device__ __forceinline__ void coh_store2(float* p, float2 v) {
    union { float2 f; unsigned long long u; } cv; cv.f = v;
    __hip_atomic_store((unsigned long long*)p, cv.u,
                       __ATOMIC_RELAXED, __HIP_MEMORY_SCOPE_AGENT);
}

// ---- two-level barrier ---------------------------------------------------
// arrive: tid0 drains wave0's stores (h-writers are wave0) and posts flag.
__device__ __forceinline__ void bar2_arrive(unsigned* flags, int bi, unsigned val) {
    if (threadIdx.x == 0) {
        asm volatile("s_waitcnt vmcnt(0)" ::: "memory");
        __hip_atomic_store(&flags[bi], val, __ATOMIC_RELAXED, __HIP_MEMORY_SCOPE_AGENT);
    }
}
// master (block 0 only): wave0 polls all 256 flags, then publishes gen.
__device__ __forceinline__ void bar2_master(const unsigned* flags, unsigned* gen,
                                            unsigned val) {
    if (threadIdx.x < 64) {
        const unsigned* f = flags + threadIdx.x * 4;
        for (;;) {
            unsigned a = __hip_atomic_load(f + 0, __ATOMIC_RELAXED, __HIP_MEMORY_SCOPE_AGENT);
            unsigned b = __hip_atomic_load(f + 1, __ATOMIC_RELAXED, __HIP_MEMORY_SCOPE_AGENT);
            unsigned c = __hip_atomic_load(f + 2, __ATOMIC_RELAXED, __HIP_MEMORY_SCOPE_AGENT);
            unsigned d = __hip_atomic_load(f + 3, __ATOMIC_RELAXED, __HIP_MEMORY_SCOPE_AGENT);
            int ok = (a >= val) && (b >= val) && (c >= val) && (d >= val);
            if (__all(ok)) break;
            __builtin_amdgcn_s_sleep(1);
        }
        if (threadIdx.x == 0)
            __hip_atomic_store(gen, val, __ATOMIC_RELAXED, __HIP_MEMORY_SCOPE_AGENT);
    }
}
// wait: one thread polls the single gen word, then block-wide sync.
__device__ __forceinline__ void bar2_wait(const unsigned* gen, unsigned val) {
    if (threadIdx.x == 0) {
        while (__hip_atomic_load(gen, __ATOMIC_RELAXED, __HIP_MEMORY_SCOPE_AGENT) < val)
            __builtin_amdgcn_s_sleep(4);
    }
    __syncthreads();
}

// ---- transpose input_seq (B,S,F) -> quad layout [s][f/4][b][4] -----------
__global__ __launch_bounds__(256) void k_transpose_input(
    const float* __restrict__ in, float4* __restrict__ xQ)
{
    __shared__ float tile[64][65];
    int s  = blockIdx.x >> 2;
    int f0 = (blockIdx.x & 3) * 64;
    int lane = threadIdx.x & 63;
    int r0   = threadIdx.x >> 6;
    for (int r = r0; r < 64; r += 4)
        tile[r][lane] = in[(size_t)r * (512 * 256) + s * 256 + f0 + lane];
    __syncthreads();
    for (int q = r0; q < 16; q += 4) {
        float4 vv = make_float4(tile[lane][4*q], tile[lane][4*q+1],
                                tile[lane][4*q+2], tile[lane][4*q+3]);
        xQ[((size_t)s * 64 + (f0 >> 2) + q) * 64 + lane] = vv;
    }
}

// ---- small weight/state transposes; encH slot0 quad-packed ---------------
__global__ __launch_bounds__(256) void k_prep(
    const float* __restrict__ We_p, const float* __restrict__ Wh_p,
    const float* __restrict__ h0,   const float* __restrict__ c0,
    const float* __restrict__ Wa,
    float* __restrict__ We_pT, float* __restrict__ Wh_pT,
    float* __restrict__ encH0, float* __restrict__ cT,
    float* __restrict__ WahT,  float* __restrict__ WaeT)
{
    int idx = blockIdx.x * blockDim.x + threadIdx.x;
    const int total = 32768 * 4 + 4096 * 2;
    for (; idx < total; idx += gridDim.x * blockDim.x) {
        if (idx < 32768) {
            int u = idx >> 6, h = idx & 63;
            We_pT[idx] = We_p[h * 512 + u];
        } else if (idx < 65536) {
            int i2 = idx - 32768; int k = i2 >> 6, i = i2 & 63;
            Wh_pT[i2] = Wh_p[i * 512 + k];
        } else if (idx < 98304) {
            int i2 = idx - 65536; int u = i2 >> 6, b = i2 & 63;
            encH0[(u >> 2) * 256 + b * 4 + (u & 3)] = h0[b * 512 + u];
        } else if (idx < 131072) {
            int i2 = idx - 98304; int u = i2 >> 6, b = i2 & 63;
            cT[i2] = c0[b * 512 + u];
        } else if (idx < 135168) {
            int i2 = idx - 131072; int j = i2 >> 6, i = i2 & 63;
            WahT[i2] = Wa[i * 128 + j];
        } else {
            int i2 = idx - 135168; int h2 = i2 >> 6, h = i2 & 63;
            WaeT[i2] = Wa[h * 128 + 64 + h2];
        }
    }
}

// ---- W_h = Wih_d.Wo[:, :512] + Whh_d ; W_c = Wih_d.Wo[:, 512:] ; b' ------
__global__ __launch_bounds__(256) void k_prep_wcomb(
    const float* __restrict__ Wih, const float* __restrict__ Whh,
    const float* __restrict__ Wo,  const float* __restrict__ bd,
    const float* __restrict__ bo,
    float* __restrict__ Wh, float* __restrict__ Wc, float* __restrict__ bprime)
{
    int r = blockIdx.x;          // 0..2047
    for (int j = threadIdx.x; j < 576; j += 256) {
        float acc = 0.f;
        for (int f = 0; f < 256; ++f)
            acc = fmaf(Wih[r * 256 + f], Wo[f * 576 + j], acc);
        if (j < 512) Wh[(size_t)r * 512 + j] = acc + Whh[(size_t)r * 512 + j];
        else         Wc[(size_t)r * 64 + (j - 512)] = acc;
    }
    if (threadIdx.x == 0) {
        float s = bd[r];
        for (int f = 0; f < 256; ++f)
            s = fmaf(Wih[r * 256 + f], bo[f], s);
        bprime[r] = s;
    }
}

// ---- g0[r][b] = Wih_d . x_last + b_d -------------------------------------
__global__ __launch_bounds__(256) void k_prep_g0(
    const float4* __restrict__ xQlast, const float* __restrict__ Wih,
    const float* __restrict__ bd, float* __restrict__ g0)
{
    int r = blockIdx.x * 4 + ((int)threadIdx.x >> 6);
    int lane = threadIdx.x & 63;
    const float4* Wih4 = (const float4*)Wih;
    float acc = bd[r];
    for (int q = 0; q < 64; ++q) {
        float4 a  = xQlast[q * 64 + lane];
        float4 wv = Wih4[(size_t)r * 64 + q];
        acc = fmaf(a.x, wv.x, acc); acc = fmaf(a.y, wv.y, acc);
        acc = fmaf(a.z, wv.z, acc); acc = fmaf(a.w, wv.w, acc);
    }
    g0[(size_t)r * 64 + lane] = acc;
}

// ---- gate-GEMM accumulation, register-prefetched (NQ = 8 or 16) ----------
template<int NQ>
__device__ __forceinline__ void accum_seg_pf(
    float acc[8], const float4* __restrict__ actQ, int qb,
    const float4* __restrict__ W4, int wstride, int u0, int lane)
{
    float4 a[NQ];
    #pragma unroll
    for (int q = 0; q < NQ; ++q)
        a[q] = actQ[(qb + q) * 64 + lane];
    #pragma unroll
    for (int q = 0; q < NQ; ++q) {
        #pragma unroll
        for (int uu = 0; uu < 2; ++uu)
            #pragma unroll
            for (int g = 0; g < 4; ++g) {
                float4 wv = W4[(size_t)(g * 512 + u0 + uu) * wstride + (qb + q)];
                float& A = acc[uu * 4 + g];
                A = fmaf(a[q].x, wv.x, A); A = fmaf(a[q].y, wv.y, A);
                A = fmaf(a[q].z, wv.z, A); A = fmaf(a[q].w, wv.w, A);
            }
    }
}

// ---- ctx-part accumulation from pre-combined register quads --------------
__device__ __forceinline__ void accum_ctx_reg(
    float acc[8], float4 c0, float4 c1,
    const float4* __restrict__ Wc4, int u0, int w)
{
    #pragma unroll
    for (int uu = 0; uu < 2; ++uu)
        #pragma unroll
        for (int g = 0; g < 4; ++g) {
            float4 w0 = Wc4[(size_t)(g * 512 + u0 + uu) * 16 + w * 2 + 0];
            float4 w1 = Wc4[(size_t)(g * 512 + u0 + uu) * 16 + w * 2 + 1];
            float& A = acc[uu * 4 + g];
            A = fmaf(c0.x, w0.x, A); A = fmaf(c0.y, w0.y, A);
            A = fmaf(c0.z, w0.z, A); A = fmaf(c0.w, w0.w, A);
            A = fmaf(c1.x, w1.x, A); A = fmaf(c1.y, w1.y, A);
            A = fmaf(c1.z, w1.z, A); A = fmaf(c1.w, w1.w, A);
        }
}

// ---- finish variant 1: additive = per-row vector (bias / b') -------------
__device__ __forceinline__ void lstm_finish_vec(
    int u0, int tid, int w, float acc[8], float2& creg,
    const float* __restrict__ addVec, float* __restrict__ houtSlot, float* smem)
{
    int lane = tid & 63;
    float* part = smem;          // [8][8][64]
    float* gsum = smem + 4096;   // [8][64]
    #pragma unroll
    for (int r = 0; r < 8; ++r)
        part[(w * 8 + r) * 64 + lane] = acc[r];
    __syncthreads();
    {
        int b = tid & 63, r = tid >> 6;
        float s = 0.f;
        #pragma unroll
        for (int ww = 0; ww < 8; ++ww)
            s += part[(ww * 8 + r) * 64 + b];
        gsum[r * 64 + b] = s;
    }
    __syncthreads();
    if (tid < 64) {
        int b = tid;
        float cc[2] = {creg.x, creg.y};
        float hv[2];
        #pragma unroll
        for (int uu = 0; uu < 2; ++uu) {
            int u = u0 + uu;
            float gi = gsum[(uu*4+0)*64 + b] + addVec[u];
            float gf = gsum[(uu*4+1)*64 + b] + addVec[512 + u];
            float gg = gsum[(uu*4+2)*64 + b] + addVec[1024 + u];
            float go = gsum[(uu*4+3)*64 + b] + addVec[1536 + u];
            float si = fsigmoid(gi), sf = fsigmoid(gf), so = fsigmoid(go);
            float tg = ftanh(gg);
            float cn = sf * cc[uu] + si * tg;
            cc[uu] = cn;
            hv[uu] = so * ftanh(cn);
        }
        creg = make_float2(cc[0], cc[1]);
        coh_store2(houtSlot + (u0 >> 2) * 256 + b * 4 + (u0 & 3),
                   make_float2(hv[0], hv[1]));
    }
}

// ---- finish variant 2: additive = row x batch buffer (g0) ----------------
__device__ __forceinline__ void lstm_finish_row(
    int u0, int tid, int w, float acc[8], float2& creg,
    const float* __restrict__ addRowB, float* __restrict__ houtSlot, float* smem)
{
    int lane = tid & 63;
    float* part = smem;
    float* gsum = smem + 4096;
    #pragma unroll
    for (int r = 0; r < 8; ++r)
        part[(w * 8 + r) * 64 + lane] = acc[r];
    __syncthreads();
    {
        int b = tid & 63, r = tid >> 6;
        float s = 0.f;
        #pragma unroll
        for (int ww = 0; ww < 8; ++ww)
            s += part[(ww * 8 + r) * 64 + b];
        gsum[r * 64 + b] = s;
    }
    __syncthreads();
    if (tid < 64) {
        int b = tid;
        float cc[2] = {creg.x, creg.y};
        float hv[2];
        #pragma unroll
        for (int uu = 0; uu < 2; ++uu) {
            int u = u0 + uu;
            float gi = gsum[(uu*4+0)*64 + b] + addRowB[(size_t)(0 * 512 + u) * 64 + b];
            float gf = gsum[(uu*4+1)*64 + b] + addRowB[(size_t)(1 * 512 + u) * 64 + b];
            float gg = gsum[(uu*4+2)*64 + b] + addRowB[(size_t)(2 * 512 + u) * 64 + b];
            float go = gsum[(uu*4+3)*64 + b] + addRowB[(size_t)(3 * 512 + u) * 64 + b];
            float si = fsigmoid(gi), sf = fsigmoid(gf), so = fsigmoid(go);
            float tg = ftanh(gg);
            float cn = sf * cc[uu] + si * tg;
            cc[uu] = cn;
            hv[uu] = so * ftanh(cn);
        }
        creg = make_float2(cc[0], cc[1]);
        coh_store2(houtSlot + (u0 >> 2) * 256 + b * 4 + (u0 & 3),
                   make_float2(hv[0], hv[1]));
    }
}

// ---- persistent encoder: overlap x-part(t+1) with barrier ----------------
__global__ __launch_bounds__(512, 2) void k_enc_persistent(
    const float4* __restrict__ xQ, float* __restrict__ encH,
    float* __restrict__ cT,
    const float* __restrict__ Wih, const float* __restrict__ Whh,
    const float* __restrict__ bias, unsigned* flags, unsigned* gen)
{
    __shared__ float smem[4608];
    int tid = threadIdx.x;
    int lane = tid & 63;
    int w = __builtin_amdgcn_readfirstlane(tid >> 6);
    int bi = blockIdx.x;
    int u0 = bi * 2;
    const float4* Wih4 = (const float4*)Wih;
    const float4* Whh4 = (const float4*)Whh;
    float2 creg = make_float2(0.f, 0.f);
    if (tid < 64) { creg.x = cT[u0 * 64 + tid]; creg.y = cT[(u0 + 1) * 64 + tid]; }
    float acc[8];
    #pragma unroll
    for (int r = 0; r < 8; ++r) acc[r] = 0.f;
    accum_seg_pf<8>(acc, xQ, w * 8, Wih4, 64, u0, lane);       // x-part t=0
    for (int t = 0; t < 512; ++t) {
        bar2_wait(gen, (unsigned)t);                            // h[t] ready
        accum_seg_pf<16>(acc, (const float4*)(encH + (size_t)t * 32768),
                         w * 16, Whh4, 128, u0, lane);
        lstm_finish_vec(u0, tid, w, acc, creg, bias,
                        encH + (size_t)(t + 1) * 32768, smem);
        bar2_arrive(flags, bi, (unsigned)(t + 1));
        if (bi == 0) bar2_master(flags, gen, (unsigned)(t + 1));
        #pragma unroll
        for (int r = 0; r < 8; ++r) acc[r] = 0.f;
        if (t + 1 < 512)   // x-part t+1 under barrier; step stride = 4096 float4
            accum_seg_pf<8>(acc, xQ + (size_t)(t + 1) * 4096, w * 8, Wih4, 64, u0, lane);
    }
    if (tid < 64) { cT[u0 * 64 + tid] = creg.x; cT[(u0 + 1) * 64 + tid] = creg.y; }
}

// ---- enc_proj + enc_attn (ba folded), round-5 form -----------------------
__global__ __launch_bounds__(256) void k_proj_attn(
    const float* __restrict__ encH,  const float* __restrict__ We_pT,
    const float* __restrict__ be_p,  const float* __restrict__ WaeT,
    const float* __restrict__ ba,
    float* __restrict__ encProj, float* __restrict__ attnPre)
{
    int lane = threadIdx.x & 63;
    int w    = __builtin_amdgcn_readfirstlane((int)threadIdx.x >> 6);
    int wid  = blockIdx.x * 4 + w;
    int b    = wid >> 6;
    int soct = wid & 63;
    float acc[8];
    float bep = be_p[lane];
    #pragma unroll
    for (int j = 0; j < 8; ++j) acc[j] = bep;
    #pragma unroll 2
    for (int q = 0; q < 128; ++q) {
        float w0 = We_pT[(4*q+0) * 64 + lane];
        float w1 = We_pT[(4*q+1) * 64 + lane];
        float w2 = We_pT[(4*q+2) * 64 + lane];
        float w3 = We_pT[(4*q+3) * 64 + lane];
        #pragma unroll
        for (int j = 0; j < 8; ++j) {
            const float4* hb4 = (const float4*)(encH + (size_t)(soct*8 + j + 1) * 32768);
            float4 hv = hb4[q * 64 + b];
            acc[j] = fmaf(hv.x, w0, acc[j]); acc[j] = fmaf(hv.y, w1, acc[j]);
            acc[j] = fmaf(hv.z, w2, acc[j]); acc[j] = fmaf(hv.w, w3, acc[j]);
        }
    }
    #pragma unroll
    for (int j = 0; j < 8; ++j)
        encProj[((size_t)b * 512 + soct * 8 + j) * 64 + lane] = acc[j];
    #pragma unroll
    for (int j = 0; j < 8; ++j) {
        float aa = ba[lane];
        for (int h2 = 0; h2 < 64; ++h2)
            aa = fmaf(__shfl(acc[j], h2), WaeT[h2 * 64 + lane], aa);
        attnPre[((size_t)b * 512 + soct * 8 + j) * 64 + lane] = aa;
    }
}

// ---- attnPre [b][s][h] -> attnPreT [b][h][s] (tile transpose) ------------
__global__ __launch_bounds__(256) void k_attn_transpose(
    const float* __restrict__ attnPre, float* __restrict__ attnPreT)
{
    __shared__ float tile[64][65];
    int b  = blockIdx.x >> 3;        // 0..63
    int s0 = (blockIdx.x & 7) * 64;  // 0..448
    int lane = threadIdx.x & 63;
    int r0   = threadIdx.x >> 6;
    for (int r = r0; r < 64; r += 4)
        tile[r][lane] = attnPre[(size_t)b * 32768 + (size_t)(s0 + r) * 64 + lane];
    __syncthreads();
    for (int r = r0; r < 64; r += 4)
        attnPreT[(size_t)b * 32768 + (size_t)r * 512 + s0 + lane] = tile[lane][r];
}

// ---- attention HALF for batch b (LDS-resident ap/ep slices) --------------
__device__ __forceinline__ void attention_half(
    int b, int tid, int w, int lane,
    const float* __restrict__ hcur,     // quad-packed h (full)
    const float* __restrict__ Wh_pT, const float* __restrict__ bh_p,
    const float* __restrict__ WahT,  const float* __restrict__ v,
    const float* __restrict__ apL,      // LDS [64][256]
    const float* __restrict__ epL,      // LDS [256][64]
    float* __restrict__ ctxsumOut,      // quad-packed (4096)
    float* __restrict__ mSOut,          // [0..63]=m, [64..127]=S per b
    float* smem)
{
    float* hq  = smem;          // 64
    float* hWa = smem + 64;     // 64
    float* sc  = smem + 128;    // 256
    float* part = smem + 384;   // 512
    float* red  = smem + 896;   // 16
    {
        const float4* h4 = (const float4*)hcur;
        float4 hv[16];
        #pragma unroll
        for (int j = 0; j < 16; ++j)
            hv[j] = h4[(w * 16 + j) * 64 + b];
        float p = 0.f;
        #pragma unroll
        for (int j = 0; j < 16; ++j) {
            int q = w * 16 + j;
            p = fmaf(hv[j].x, Wh_pT[(4*q+0) * 64 + lane], p);
            p = fmaf(hv[j].y, Wh_pT[(4*q+1) * 64 + lane], p);
            p = fmaf(hv[j].z, Wh_pT[(4*q+2) * 64 + lane], p);
            p = fmaf(hv[j].w, Wh_pT[(4*q+3) * 64 + lane], p);
        }
        part[w * 64 + lane] = p;
    }
    __syncthreads();
    if (tid < 64) {
        float s = bh_p[tid];
        #pragma unroll
        for (int ww = 0; ww < 8; ++ww) s += part[ww * 64 + tid];
        hq[tid] = s;
    }
    __syncthreads();
    if (tid < 64) {
        float s = 0.f;
        for (int j = 0; j < 64; ++j)
            s = fmaf(hq[j], WahT[j * 64 + tid], s);
        hWa[tid] = s;
    }
    __syncthreads();
    {
        int sp  = tid & 255;
        int hh0 = (tid >> 8) * 32;
        float acc = 0.f;
        for (int j = 0; j < 32; ++j) {
            int h = hh0 + j;
            float e = ftanh(hWa[h] + apL[h * 256 + sp]);
            acc = fmaf(v[h], e, acc);
        }
        part[tid] = acc;
    }
    __syncthreads();
    if (tid < 256)
        sc[tid] = part[tid] + part[256 + tid];
    __syncthreads();
    if (tid < 256) {
        float x = sc[tid];
        float m = x;
        #pragma unroll
        for (int off = 32; off > 0; off >>= 1)
            m = fmaxf(m, __shfl_xor(m, off));
        if (lane == 0) red[w] = m;
    }
    __syncthreads();
    if (tid == 0)
        red[8] = fmaxf(fmaxf(red[0], red[1]), fmaxf(red[2], red[3]));
    __syncthreads();
    float M = red[8];
    if (tid < 256) {
        float e = __expf(sc[tid] - M);
        sc[tid] = e;
        float s = e;
        #pragma unroll
        for (int off = 32; off > 0; off >>= 1)
            s += __shfl_xor(s, off);
        if (lane == 0) red[w] = s;
    }
    __syncthreads();
    if (tid == 0)
        red[9] = ((red[0] + red[1]) + (red[2] + red[3]));
    __syncthreads();
    {
        float a = 0.f;
        for (int i = 0; i < 32; ++i) {
            int sp2 = w * 32 + i;
            a = fmaf(sc[sp2], epL[sp2 * 64 + lane], a);
        }
        part[w * 64 + lane] = a;
    }
    __syncthreads();
    if (tid < 64) {
        float s = 0.f;
        #pragma unroll
        for (int ww = 0; ww < 8; ++ww) s += part[ww * 64 + tid];
        coh_store(&ctxsumOut[(tid >> 2) * 256 + b * 4 + (tid & 3)], s);
    }
    if (tid == 0) {
        coh_store(&mSOut[b], M);
        coh_store(&mSOut[64 + b], red[9]);
    }
    __syncthreads();
}

// ---- combined ctx quads for a wave (lane = b) ----------------------------
__device__ __forceinline__ void load_ctx_quads(
    int t, int w, int lane,
    const float* __restrict__ ctxsumH, const float* __restrict__ mSbuf,
    float4& c0, float4& c1)
{
    const float* mS = mSbuf + (size_t)(t - 1) * 256;
    float m0 = mS[lane],       S0 = mS[64 + lane];
    float m1 = mS[128 + lane], S1 = mS[192 + lane];
    float M  = fmaxf(m0, m1);
    float e0 = __expf(m0 - M), e1 = __expf(m1 - M);
    float inv = 1.0f / (e0 * S0 + e1 * S1);
    e0 *= inv; e1 *= inv;
    const float4* a0 = (const float4*)(ctxsumH + (size_t)(t - 1) * 8192);
    const float4* a1 = (const float4*)(ctxsumH + (size_t)(t - 1) * 8192 + 4096);
    float4 x0 = a0[(w * 2 + 0) * 64 + lane];
    float4 y0 = a1[(w * 2 + 0) * 64 + lane];
    float4 x1 = a0[(w * 2 + 1) * 64 + lane];
    float4 y1 = a1[(w * 2 + 1) * 64 + lane];
    c0 = make_float4(e0 * x0.x + e1 * y0.x, e0 * x0.y + e1 * y0.y,
                     e0 * x0.z + e1 * y0.z, e0 * x0.w + e1 * y0.w);
    c1 = make_float4(e0 * x1.x + e1 * y1.x, e0 * x1.y + e1 * y1.y,
                     e0 * x1.z + e1 * y1.z, e0 * x1.w + e1 * y1.w);
}

// ---- persistent decoder: 128 attn-half blocks + 128 LSTM blocks ----------
extern __shared__ float dynsmem[];
__global__ __launch_bounds__(512) void k_dec_persistent(
    const float* __restrict__ encHend,
    float* __restrict__ dechH,            // [96][quad 32768]
    float* __restrict__ cT,
    const float* __restrict__ Whh,        // t=0 h-part
    const float* __restrict__ Wh,         // t>=1 fused h-part
    const float* __restrict__ Wc,         // ctx part
    const float* __restrict__ g0, const float* __restrict__ bprime,
    const float* __restrict__ Wh_pT, const float* __restrict__ bh_p,
    const float* __restrict__ WahT,  const float* __restrict__ v,
    const float* __restrict__ attnPreT, const float* __restrict__ encProj,
    float* __restrict__ ctxsumH,          // [96][2][4096]
    float* __restrict__ mSbuf,            // [96][256]
    unsigned* flags, unsigned* gen)
{
    float* smem = dynsmem;                // 4608 floats scratch
    float* apL  = dynsmem + 4608;         // 16384: [h][s']
    float* epL  = apL + 16384;            // 16384: [s'][h2]
    int tid = threadIdx.x;
    int lane = tid & 63;
    int w = __builtin_amdgcn_readfirstlane(tid >> 6);
    int bi = blockIdx.x;
    if (bi < 128) {
        int b = bi & 63, half = bi >> 6;
        {
            const float4* src = (const float4*)(attnPreT + (size_t)b * 32768 + half * 256);
            float4* dst = (float4*)apL;
            for (int i = tid; i < 4096; i += 512) {
                int h = i >> 6, qc = i & 63;
                dst[i] = src[(size_t)h * 128 + qc];
            }
        }
        {
            const float4* src = (const float4*)(encProj + ((size_t)b * 512 + half * 256) * 64);
            float4* dst = (float4*)epL;
            for (int i = tid; i < 4096; i += 512)
                dst[i] = src[i];
        }
        __syncthreads();
        for (int t = 0; t < 96; ++t) {
            bar2_wait(gen, (unsigned)t);
            const float* hc = t ? dechH + (size_t)(t - 1) * 32768 : encHend;
            attention_half(b, tid, w, lane, hc, Wh_pT, bh_p, WahT, v,
                           apL, epL,
                           ctxsumH + (size_t)t * 8192 + half * 4096,
                           mSbuf + (size_t)t * 256 + half * 128, smem);
            bar2_arrive(flags, bi, (unsigned)(t + 1));
            if (bi == 0) bar2_master(flags, gen, (unsigned)(t + 1));
        }
    } else {
        int u0A = (bi - 128) * 2;
        int u0B = u0A + 256;
        const float4* Whh4 = (const float4*)Whh;
        const float4* Wh4  = (const float4*)Wh;
        const float4* Wc4  = (const float4*)Wc;
        float2 cA = make_float2(0.f, 0.f), cB = cA;
        if (tid < 64) {
            cA.x = cT[u0A * 64 + tid]; cA.y = cT[(u0A + 1) * 64 + tid];
            cB.x = cT[u0B * 64 + tid]; cB.y = cT[(u0B + 1) * 64 + tid];
        }
        for (int t = 0; t < 96; ++t) {
            bar2_wait(gen, (unsigned)t);
            const float* hc = t ? dechH + (size_t)(t - 1) * 32768 : encHend;
            float* hn = dechH + (size_t)t * 32768;
            float acc[8];
            if (t == 0) {
                #pragma unroll
                for (int r = 0; r < 8; ++r) acc[r] = 0.f;
                accum_seg_pf<16>(acc, (const float4*)hc, w * 16, Whh4, 128, u0A, lane);
                lstm_finish_row(u0A, tid, w, acc, cA, g0, hn, smem);
                #pragma unroll
                for (int r = 0; r < 8; ++r) acc[r] = 0.f;
                accum_seg_pf<16>(acc, (const float4*)hc, w * 16, Whh4, 128, u0B, lane);
                lstm_finish_row(u0B, tid, w, acc, cB, g0, hn, smem);
            } else {
                float4 cq0, cq1;
                load_ctx_quads(t, w, lane, ctxsumH, mSbuf, cq0, cq1);
                #pragma unroll
                for (int r = 0; r < 8; ++r) acc[r] = 0.f;
                accum_seg_pf<16>(acc, (const float4*)hc, w * 16, Wh4, 128, u0A, lane);
                accum_ctx_reg(acc, cq0, cq1, Wc4, u0A, w);
                lstm_finish_vec(u0A, tid, w, acc, cA, bprime, hn, smem);
                #pragma unroll
                for (int r = 0; r < 8; ++r) acc[r] = 0.f;
                accum_seg_pf<16>(acc, (const float4*)hc, w * 16, Wh4, 128, u0B, lane);
                accum_ctx_reg(acc, cq0, cq1, Wc4, u0B, w);
                lstm_finish_vec(u0B, tid, w, acc, cB, bprime, hn, smem);
            }
            bar2_arrive(flags, bi, (unsigned)(t + 1));
        }
    }
}

// ---- post-pass: dout[b][tau] = Wo[255].[h^{(tau+1)}; ctx_tau] + bo[255] --
__global__ __launch_bounds__(256) void k_dout(
    const float* __restrict__ dechH,
    const float* __restrict__ ctxsumH, const float* __restrict__ mSbuf,
    const float* __restrict__ Wo, const float* __restrict__ bo,
    float* __restrict__ dout)
{
    __shared__ float part[256];
    int tau = blockIdx.x;            // 0..95
    int tid = threadIdx.x;
    int lane = tid & 63;             // = b
    int w = tid >> 6;                // 0..3
    const float* hq = dechH + (size_t)tau * 32768;
    const float* wrow = Wo + 255 * 576;
    float acc = 0.f;
    for (int i = w * 128; i < w * 128 + 128; ++i)
        acc = fmaf(wrow[i], hq[(i >> 2) * 256 + lane * 4 + (i & 3)], acc);
    part[w * 64 + lane] = acc;
    __syncthreads();
    if (tid < 64) {
        int b = tid;
        const float* mS = mSbuf + (size_t)tau * 256;
        float m0 = mS[b],       S0 = mS[64 + b];
        float m1 = mS[128 + b], S1 = mS[192 + b];
        float M  = fmaxf(m0, m1);
        float e0 = __expf(m0 - M), e1 = __expf(m1 - M);
        float inv = 1.0f / (e0 * S0 + e1 * S1);
        e0 *= inv; e1 *= inv;
        const float* cs0 = ctxsumH + (size_t)tau * 8192;
        const float* cs1 = cs0 + 4096;
        float a2 = bo[255];
        for (int h2 = 0; h2 < 64; ++h2) {
            int idx = (h2 >> 2) * 256 + b * 4 + (h2 & 3);
            a2 = fmaf(wrow[512 + h2], e0 * cs0[idx] + e1 * cs1[idx], a2);
        }
        float s = a2 + part[b] + part[64 + b] + part[128 + b] + part[192 + b];
        dout[b * 96 + tau] = s;
    }
}

} // namespace

extern "C" void kernel_launch(void* const* d_in, const int* in_sizes, int n_in,
                              void* d_out, int out_size, void* d_ws, size_t ws_size,
                              hipStream_t stream)
{
    (void)in_sizes; (void)n_in; (void)out_size; (void)ws_size;
    const float* input_seq = (const float*)d_in[0];
    const float* h0     = (const float*)d_in[1];
    const float* c0     = (const float*)d_in[2];
    const float* W_ih_e = (const float*)d_in[3];
    const float* W_hh_e = (const float*)d_in[4];
    const float* b_e    = (const float*)d_in[5];
    const float* W_ih_d = (const float*)d_in[6];
    const float* W_hh_d = (const float*)d_in[7];
    const float* b_d    = (const float*)d_in[8];
    const float* We_p   = (const float*)d_in[9];
    const float* be_p   = (const float*)d_in[10];
    const float* Wh_p   = (const float*)d_in[11];
    const float* bh_p   = (const float*)d_in[12];
    const float* Wa     = (const float*)d_in[13];
    const float* ba     = (const float*)d_in[14];
    const float* v      = (const float*)d_in[15];
    const float* Wo     = (const float*)d_in[16];
    const float* bo     = (const float*)d_in[17];
    float* out = (float*)d_out;

    unsigned* encFlags = (unsigned*)d_ws;       // 256 words
    unsigned* decFlags = encFlags + 256;        // 256 words
    unsigned* encGen   = decFlags + 256;        // 1 word
    unsigned* decGen   = encGen + 16;           // 1 word (separate line)
    float* ws       = (float*)d_ws + 1024;      // 4KB offset
    float* xT       = ws;                       // 8388608 (dead after enc/g0)
    float* encH     = xT + 8388608;             // 513*32768 = 16809984
    float* cT       = encH + 16809984;          // 32768
    float* We_pT    = cT + 32768;               // 32768
    float* Wh_pT    = We_pT + 32768;            // 32768
    float* WahT     = Wh_pT + 32768;            // 4096
    float* WaeT     = WahT + 4096;              // 4096
    float* encProj  = WaeT + 4096;              // 2097152
    float* attnPre  = encProj + 2097152;        // 2097152
    float* dechH    = attnPre + 2097152;        // 96*32768 = 3145728
    float* ctxsumH  = dechH + 3145728;          // 96*2*4096 = 786432
    float* mSbuf    = ctxsumH + 786432;         // 96*256 = 24576
    float* Wh       = mSbuf + 24576;            // 2048*512 = 1048576
    float* Wc       = Wh + 1048576;             // 2048*64 = 131072
    float* bprime   = Wc + 131072;              // 2048
    float* g0       = bprime + 2048;            // 2048*64 = 131072
    float* attnPreT = xT;                       // aliases dead xT region (2M)

    (void)hipFuncSetAttribute((const void*)k_dec_persistent,
                              hipFuncAttributeMaxDynamicSharedMemorySize, 149504);

    hipMemsetAsync(d_ws, 0, 4096, stream);      // zero barrier flags + gens
    k_transpose_input<<<2048, 256, 0, stream>>>(input_seq, (float4*)xT);
    k_prep<<<544, 256, 0, stream>>>(We_p, Wh_p, h0, c0, Wa,
                                    We_pT, Wh_pT, encH, cT, WahT, WaeT);
    k_prep_wcomb<<<2048, 256, 0, stream>>>(W_ih_d, W_hh_d, Wo, b_d, bo,
                                           Wh, Wc, bprime);
    k_prep_g0<<<512, 256, 0, stream>>>((const float4*)(xT + (size_t)511 * 16384),
                                       W_ih_d, b_d, g0);
    k_enc_persistent<<<256, 512, 0, stream>>>((const float4*)xT, encH, cT,
                                              W_ih_e, W_hh_e, b_e,
                                              encFlags, encGen);
    k_proj_attn<<<1024, 256, 0, stream>>>(encH, We_pT, be_p, WaeT, ba,
                                          encProj, attnPre);
    k_attn_transpose<<<512, 256, 0, stream>>>(attnPre, attnPreT);
    k_dec_persistent<<<256, 512, 149504, stream>>>(encH + (size_t)512 * 32768,
                                                   dechH, cT,
                                                   W_hh_d, Wh, Wc, g0, bprime,
                                                   Wh_pT, bh_p, WahT, v,
                                                   attnPreT, encProj,
                                                   ctxsumH, mSbuf,
                                                   decFlags, decGen);
    k_dout<<<96, 256, 0, stream>>>(dechH, ctxsumH, mSbuf, Wo, bo, out);
}